// Round 7
// baseline (619.866 us; speedup 1.0000x reference)
//
#include <hip/hip_runtime.h>
#include <hip/hip_bf16.h>
#include <math.h>

#define NPTS 40000
#define KNB 16
#define CH 128

typedef unsigned short u16;
typedef __attribute__((ext_vector_type(8))) short bf16x8;
typedef __attribute__((ext_vector_type(4))) float f32x4;

__device__ __forceinline__ float gelu_f(float v) {
  const float u = 0.7978845608028654f * (v + 0.044715f * v * v * v);
  const float t = __builtin_amdgcn_exp2f(-2.8853900817779268f * u);
  return v * __builtin_amdgcn_rcpf(1.0f + t);
}

__device__ __forceinline__ float bnscale(float g) {
  return g * rsqrtf(1.0f + 1e-5f);
}

__device__ __forceinline__ u16 f2bf(float x) {
  union { __hip_bfloat16 b; u16 u; } cv;
  cv.b = __float2bfloat16(x);
  return cv.u;
}

__device__ __forceinline__ float bf2f(u16 u) {
  union { float f; unsigned int i; } cv;
  cv.i = ((unsigned int)u) << 16;
  return cv.f;
}

__device__ __forceinline__ void bf16split(float x, u16& hi, u16& lo) {
  hi = f2bf(x);
  lo = f2bf(x - bf2f(hi));
}

// ---------------- knn_spse_4 + BN0 -> bf16 hi/lo ----------------
__global__ __launch_bounds__(128) void spse_kernel(
    const float* __restrict__ x, const float* __restrict__ xyz,
    const int* __restrict__ knn, const float* __restrict__ sm,
    const float* __restrict__ sc, const float* __restrict__ sh,
    const float* __restrict__ g0, const float* __restrict__ b0,
    u16* __restrict__ oh, u16* __restrict__ ol) {
  const int n = blockIdx.x;
  const int c = threadIdx.x;
  __shared__ float sr[KNB][3];
  __shared__ float sf[KNB][4];
  if (c < KNB) {
    const int j = knn[n * KNB + c];
    sr[c][0] = xyz[j * 3 + 0] - xyz[n * 3 + 0];
    sr[c][1] = xyz[j * 3 + 1] - xyz[n * 3 + 1];
    sr[c][2] = xyz[j * 3 + 2] - xyz[n * 3 + 2];
    float f0 = x[j * 4 + 0] - x[n * 4 + 0];
    float f1 = x[j * 4 + 1] - x[n * 4 + 1];
    float f2 = x[j * 4 + 2] - x[n * 4 + 2];
    float f3 = x[j * 4 + 3] - x[n * 4 + 3];
    sf[c][0] = f0 * f0; sf[c][1] = f1 * f1;
    sf[c][2] = f2 * f2; sf[c][3] = f3 * f3;
  }
  __syncthreads();
  const float m0 = sm[c], m1 = sm[CH + c], m2 = sm[2 * CH + c];
  const float m4 = sm[4 * CH + c], m5 = sm[5 * CH + c], m6 = sm[6 * CH + c];
  const float m8 = sm[8 * CH + c], m9 = sm[9 * CH + c], m10 = sm[10 * CH + c];
  float c0 = sc[c];          c0 *= c0;
  float c1 = sc[CH + c];     c1 *= c1;
  float c2 = sc[2 * CH + c]; c2 *= c2;
  float h2 = sh[c];          h2 *= h2;
  float e = 0.0f;
#pragma unroll
  for (int k = 0; k < KNB; k++) {
    const float r0 = sr[k][0], r1 = sr[k][1], r2 = sr[k][2];
    const float d0 = fmaf(r2, m2, fmaf(r1, m1, r0 * m0));
    const float d1 = fmaf(r2, m6, fmaf(r1, m5, r0 * m4));
    const float d2 = fmaf(r2, m10, fmaf(r1, m9, r0 * m8));
    e = fmaf(d0, d0, e);
    e = fmaf(d1, d1, e);
    e = fmaf(d2, d2, e);
    e = fmaf(sf[k][0], c0, e);
    e = fmaf(sf[k][1], c1, e);
    e = fmaf(sf[k][2], c2, e);
    e = fmaf(sf[k][3], h2, e);
  }
  const float v = sqrtf(e * (1.0f / KNB)) * bnscale(g0[c]) + b0[c];
  u16 hi, lo; bf16split(v, hi, lo);
  const size_t idx = (size_t)n * CH + c;
  oh[idx] = hi; ol[idx] = lo;
}

// ---------------- LFP gather + PE + max + BN + residual (h as hi/lo) ----------------
// 256 thr = 16 points, 16 lanes/point, 8 ch/lane, 16B bf16x8 gathers
__global__ __launch_bounds__(256) void lfp_kernel(
    const u16* __restrict__ xp, const int* __restrict__ knn,
    const float* __restrict__ xyz, const float* __restrict__ coor,
    const float* __restrict__ scale, const float* __restrict__ g,
    const float* __restrict__ b, u16* __restrict__ hh, u16* __restrict__ hl) {
  const int t = threadIdx.x;
  const int bid = blockIdx.x;
  __shared__ int si[16][KNB];
  __shared__ float sr[16][KNB][3];
  {
    const int pp = t >> 4, kk = t & 15;
    const int n = bid * 16 + pp;
    const int j = knn[n * KNB + kk];
    si[pp][kk] = j;
    sr[pp][kk][0] = xyz[j * 3 + 0] - xyz[n * 3 + 0];
    sr[pp][kk][1] = xyz[j * 3 + 1] - xyz[n * 3 + 1];
    sr[pp][kk][2] = xyz[j * 3 + 2] - xyz[n * 3 + 2];
  }
  __syncthreads();
  const int p = t >> 4, d8 = t & 15;   // channels c = d8*8 .. d8*8+7
  const int n = bid * 16 + p;
  const float c0a = coor[d8 * 2],     c1a = coor[32 + d8 * 2],     c2a = coor[64 + d8 * 2];
  const float c0b = coor[d8 * 2 + 1], c1b = coor[32 + d8 * 2 + 1], c2b = coor[64 + d8 * 2 + 1];
  float s2a = scale[d8 * 2];     s2a *= s2a;
  float s2b = scale[d8 * 2 + 1]; s2b *= s2b;
  float a[8];
#pragma unroll
  for (int e = 0; e < 8; e++) a[e] = -3.0e38f;
#pragma unroll
  for (int k = 0; k < KNB; k++) {
    const int j = si[p][k];
    const float r0 = sr[p][k][0], r1 = sr[p][k][1], r2 = sr[p][k][2];
    const float pea = fmaf(r2, c2a, fmaf(r1, c1a, r0 * c0a)) * s2a;
    const float peb = fmaf(r2, c2b, fmaf(r1, c1b, r0 * c0b)) * s2b;
    const bf16x8 v = *(const bf16x8*)(xp + (size_t)j * CH + d8 * 8);
#pragma unroll
    for (int e = 0; e < 4; e++) a[e] = fmaxf(a[e], bf2f((u16)v[e]) + pea);
#pragma unroll
    for (int e = 4; e < 8; e++) a[e] = fmaxf(a[e], bf2f((u16)v[e]) + peb);
  }
  const size_t off = (size_t)n * CH + d8 * 8;
  union { u16 a[8]; uint4 v; } ih, il, oh, ol;
  ih.v = *(const uint4*)(hh + off);
  il.v = *(const uint4*)(hl + off);
#pragma unroll
  for (int e = 0; e < 8; e++) {
    const int c = d8 * 8 + e;
    const float nv = bf2f(ih.a[e]) + bf2f(il.a[e]) + a[e] * bnscale(g[c]) + b[c];
    u16 hi, lo; bf16split(nv, hi, lo);
    oh.a[e] = hi; ol.a[e] = lo;
  }
  *(uint4*)(hh + off) = oh.v;
  *(uint4*)(hl + off) = ol.v;
}

// ---------------- weight prep: transpose + bf16 hi/lo (no swizzle; all reg loads) ----
// dst (u16): nw1@0 [256][128], nw2@32768 [128][256], mw1[j]@65536+j*65536 [512][128],
// mw2[j]@262144+j*65536 [128][512], lproj[i]@458752+i*16384 [128][128], post@524288 [256][128]
__global__ __launch_bounds__(256) void prep_weights(
    const float* __restrict__ nw1, const float* __restrict__ nw2,
    const float* __restrict__ mw1, const float* __restrict__ mw2,
    const float* __restrict__ lproj, const float* __restrict__ pw,
    const float* __restrict__ pg, u16* __restrict__ th, u16* __restrict__ tl) {
  const int idx = blockIdx.x * 256 + threadIdx.x;
  const float* src;
  int local, Kd, Nd, dst;
  float scale = 1.0f;
  if (idx < 32768)        { src = nw1; local = idx;          Kd = 128; Nd = 256; dst = 0; }
  else if (idx < 65536)   { src = nw2; local = idx - 32768;  Kd = 256; Nd = 128; dst = 32768; }
  else if (idx < 262144)  { int j = (idx - 65536) >> 16;  local = (idx - 65536) & 65535;
                            src = mw1 + j * 65536; Kd = 128; Nd = 512; dst = 65536 + j * 65536; }
  else if (idx < 458752)  { int j = (idx - 262144) >> 16; local = (idx - 262144) & 65535;
                            src = mw2 + j * 65536; Kd = 512; Nd = 128; dst = 262144 + j * 65536; }
  else if (idx < 524288)  { int i = (idx - 458752) >> 14; local = (idx - 458752) & 16383;
                            src = lproj + i * 16384; Kd = 128; Nd = 128; dst = 458752 + i * 16384; }
  else if (idx < 557056)  { local = idx - 524288; src = pw; Kd = 128; Nd = 256; dst = 524288;
                            scale = bnscale(pg[local >> 8]); }
  else return;
  const int k = local / Nd, n = local % Nd;
  const float v = src[local] * scale;
  u16 hi, lo; bf16split(v, hi, lo);
  const int o = dst + n * Kd + k;
  th[o] = hi; tl[o] = lo;
}

// folded post bias: fb[n] = sum_k pb[k] * pw[k][n]
__global__ __launch_bounds__(256) void fold_pb(const float* __restrict__ pw,
                                               const float* __restrict__ pb,
                                               float* __restrict__ fb) {
  const int t = threadIdx.x;
  float a = 0.0f;
  for (int k = 0; k < 128; k++) a = fmaf(pb[k], pw[k * 256 + t], a);
  fb[t] = a;
}

// ---------------- barrier-free streaming K=128 GEMM, W in registers ----------------
// EPI: 0 -> bf16 store (xp); 2 -> v+bias -> f32 out
template <int EPI>
__global__ __launch_bounds__(256, 2) void k128_reg(
    const u16* __restrict__ Ahi, const u16* __restrict__ Alo,
    const u16* __restrict__ Wth, const u16* __restrict__ Wtl,
    const float* __restrict__ p0, u16* __restrict__ outu,
    float* __restrict__ outf, int ostride, int ntiles) {
  const int t = threadIdx.x, lane = t & 63, w = t >> 6;
  const int col0 = blockIdx.y * 128;
  const int wm0 = (w >> 1) * 32, wn0 = (w & 1) * 64;
  const int lc = lane & 15, lq = lane >> 4;
  const int lq8 = lq * 8, lq4 = lq * 4;

  bf16x8 wh[4][4], wl[4][4];
  float bv[4];
#pragma unroll
  for (int nf = 0; nf < 4; nf++) {
    const int nr = col0 + wn0 + nf * 16 + lc;
    const u16* wr = Wth + (size_t)nr * 128;
    const u16* wr2 = Wtl + (size_t)nr * 128;
#pragma unroll
    for (int ks = 0; ks < 4; ks++) {
      wh[nf][ks] = *(const bf16x8*)(wr + ks * 32 + lq8);
      wl[nf][ks] = *(const bf16x8*)(wr2 + ks * 32 + lq8);
    }
    bv[nf] = (EPI == 0) ? 0.0f : p0[nr];
  }

  const f32x4 zz = {0.0f, 0.0f, 0.0f, 0.0f};
  for (int tile = blockIdx.x; tile < ntiles; tile += gridDim.x) {
    const int row0 = tile * 64;
    f32x4 acc[2][4];
#pragma unroll
    for (int mf = 0; mf < 2; mf++)
#pragma unroll
      for (int nf = 0; nf < 4; nf++) acc[mf][nf] = zz;
#pragma unroll
    for (int ks = 0; ks < 4; ks++) {
      bf16x8 ah[2], al[2];
#pragma unroll
      for (int mf = 0; mf < 2; mf++) {
        const size_t ao = (size_t)(row0 + wm0 + mf * 16 + lc) * 128 + ks * 32 + lq8;
        ah[mf] = *(const bf16x8*)(Ahi + ao);
        al[mf] = *(const bf16x8*)(Alo + ao);
      }
#pragma unroll
      for (int mf = 0; mf < 2; mf++)
#pragma unroll
        for (int nf = 0; nf < 4; nf++) {
          acc[mf][nf] = __builtin_amdgcn_mfma_f32_16x16x32_bf16(ah[mf], wh[nf][ks], acc[mf][nf], 0, 0, 0);
          acc[mf][nf] = __builtin_amdgcn_mfma_f32_16x16x32_bf16(ah[mf], wl[nf][ks], acc[mf][nf], 0, 0, 0);
          acc[mf][nf] = __builtin_amdgcn_mfma_f32_16x16x32_bf16(al[mf], wh[nf][ks], acc[mf][nf], 0, 0, 0);
        }
    }
#pragma unroll
    for (int mf = 0; mf < 2; mf++)
#pragma unroll
      for (int q = 0; q < 4; q++) {
        const int r = row0 + wm0 + mf * 16 + lq4 + q;
#pragma unroll
        for (int nf = 0; nf < 4; nf++) {
          const int col = col0 + wn0 + nf * 16 + lc;
          const size_t off = (size_t)r * ostride + col;
          const float v = acc[mf][nf][q];
          if (EPI == 0) outu[off] = f2bf(v);
          else          outf[off] = v + bv[nf];
        }
      }
  }
}

// ---------------- fused MLP: h' = [h +] BN(gelu(h@W1+b1)@W2) ----------------
// 512 thr = 8 waves, 64 rows/block (625 exact blocks). Weights straight
// global->reg (used once per block; L2-hot). Hidden act in LDS only
// (bf16-hi, 64-window XOR swizzle). ONE barrier per block.
// w1: wave owns HID/8 hidden cols, all 64 rows. w2: 2x4 wave grid on 64x128 out.
template <int HID, bool RES>
__global__ __launch_bounds__(512, 1) void mlp_fused(
    const u16* __restrict__ Ahi, const u16* __restrict__ Alo,
    const u16* __restrict__ W1t, const u16* __restrict__ W1tl,
    const u16* __restrict__ W2t, const u16* __restrict__ W2tl,
    const float* __restrict__ b1, const float* __restrict__ g,
    const float* __restrict__ bb, u16* __restrict__ hh, u16* __restrict__ hl) {
  constexpr int HID8 = HID / 8;    // hidden cols per wave
  constexpr int NF1 = HID8 / 16;   // 4 (HID=512) or 2 (HID=256)
  constexpr int NKS2 = HID / 32;
  __shared__ __align__(16) u16 act[64 * HID];
  const int t = threadIdx.x, lane = t & 63, w = t >> 6;
  const int row0 = blockIdx.x * 64;
  const int lc = lane & 15, lq = lane >> 4;
  const int lq8 = lq * 8, lq4 = lq * 4;
  const int cw0 = w * HID8;

  const f32x4 zz = {0.0f, 0.0f, 0.0f, 0.0f};
  // ---- w1 phase: acc1[64 rows][wave's HID8 cols] ----
  f32x4 acc1[4][NF1];
#pragma unroll
  for (int mf = 0; mf < 4; mf++)
#pragma unroll
    for (int nf = 0; nf < NF1; nf++) acc1[mf][nf] = zz;

#pragma unroll
  for (int ks = 0; ks < 4; ks++) {
    bf16x8 ah[4], al[4];
#pragma unroll
    for (int mf = 0; mf < 4; mf++) {
      const size_t ao = (size_t)(row0 + mf * 16 + lc) * 128 + ks * 32 + lq8;
      ah[mf] = *(const bf16x8*)(Ahi + ao);
      al[mf] = *(const bf16x8*)(Alo + ao);
    }
    bf16x8 w1h[NF1], w1l[NF1];
#pragma unroll
    for (int nf = 0; nf < NF1; nf++) {
      const size_t wo = (size_t)(cw0 + nf * 16 + lc) * 128 + ks * 32 + lq8;
      w1h[nf] = *(const bf16x8*)(W1t + wo);
      w1l[nf] = *(const bf16x8*)(W1tl + wo);
    }
#pragma unroll
    for (int mf = 0; mf < 4; mf++)
#pragma unroll
      for (int nf = 0; nf < NF1; nf++) {
        acc1[mf][nf] = __builtin_amdgcn_mfma_f32_16x16x32_bf16(ah[mf], w1h[nf], acc1[mf][nf], 0, 0, 0);
        acc1[mf][nf] = __builtin_amdgcn_mfma_f32_16x16x32_bf16(ah[mf], w1l[nf], acc1[mf][nf], 0, 0, 0);
        acc1[mf][nf] = __builtin_amdgcn_mfma_f32_16x16x32_bf16(al[mf], w1h[nf], acc1[mf][nf], 0, 0, 0);
      }
  }
  // ---- bias + gelu -> act LDS (XOR-swizzled) ----
  float b1v[NF1];
#pragma unroll
  for (int nf = 0; nf < NF1; nf++) b1v[nf] = b1[cw0 + nf * 16 + lc];
#pragma unroll
  for (int mf = 0; mf < 4; mf++)
#pragma unroll
    for (int nf = 0; nf < NF1; nf++)
#pragma unroll
      for (int q = 0; q < 4; q++) {
        const int row = mf * 16 + lq4 + q;
        const int col = cw0 + nf * 16 + lc;
        const int cs = (col & ~63) | ((col & 63) ^ ((row & 7) << 3));
        act[row * HID + cs] = f2bf(gelu_f(acc1[mf][nf][q] + b1v[nf]));
      }
  __syncthreads();

  // ---- w2 phase: out[64 x 128], wave = (row-half, col-quarter) ----
  const int wr = w >> 2, wc = w & 3;
  f32x4 acc[2][2];
#pragma unroll
  for (int mf = 0; mf < 2; mf++)
#pragma unroll
    for (int nf = 0; nf < 2; nf++) acc[mf][nf] = zz;

#pragma unroll
  for (int ks = 0; ks < NKS2; ks++) {
    bf16x8 af[2];
#pragma unroll
    for (int mf = 0; mf < 2; mf++) {
      const int r = wr * 32 + mf * 16 + lc;
      const int cb = ks * 32 + lq8;
      const int cs = (cb & ~63) | ((cb & 63) ^ ((r & 7) << 3));
      af[mf] = *(const bf16x8*)(act + r * HID + cs);
    }
    bf16x8 w2h[2], w2l[2];
#pragma unroll
    for (int nf = 0; nf < 2; nf++) {
      const size_t wo = (size_t)(wc * 32 + nf * 16 + lc) * HID + ks * 32 + lq8;
      w2h[nf] = *(const bf16x8*)(W2t + wo);
      w2l[nf] = *(const bf16x8*)(W2tl + wo);
    }
#pragma unroll
    for (int mf = 0; mf < 2; mf++)
#pragma unroll
      for (int nf = 0; nf < 2; nf++) {
        acc[mf][nf] = __builtin_amdgcn_mfma_f32_16x16x32_bf16(af[mf], w2h[nf], acc[mf][nf], 0, 0, 0);
        acc[mf][nf] = __builtin_amdgcn_mfma_f32_16x16x32_bf16(af[mf], w2l[nf], acc[mf][nf], 0, 0, 0);
      }
  }

  // ---- epilogue: BN (+residual) -> h hi/lo ----
  float S0[2], S1[2];
#pragma unroll
  for (int nf = 0; nf < 2; nf++) {
    const int col = wc * 32 + nf * 16 + lc;
    S0[nf] = bnscale(g[col]);
    S1[nf] = bb[col];
  }
#pragma unroll
  for (int mf = 0; mf < 2; mf++)
#pragma unroll
    for (int q = 0; q < 4; q++) {
      const int r = row0 + wr * 32 + mf * 16 + lq4 + q;
#pragma unroll
      for (int nf = 0; nf < 2; nf++) {
        const int col = wc * 32 + nf * 16 + lc;
        const size_t off = (size_t)r * CH + col;
        float v = acc[mf][nf][q] * S0[nf] + S1[nf];
        if (RES) v += bf2f(hh[off]) + bf2f(hl[off]);
        u16 hi, lo; bf16split(v, hi, lo);
        hh[off] = hi; hl[off] = lo;
      }
    }
}

extern "C" void kernel_launch(void* const* d_in, const int* in_sizes, int n_in,
                              void* d_out, int out_size, void* d_ws, size_t ws_size,
                              hipStream_t stream) {
  const float* x    = (const float*)d_in[0];
  const float* xyz  = (const float*)d_in[1];
  const int*   knn  = (const int*)d_in[2];
  const float* sm   = (const float*)d_in[3];
  const float* scc  = (const float*)d_in[4];
  const float* shh  = (const float*)d_in[5];
  const float* bn0g = (const float*)d_in[6];
  const float* bn0b = (const float*)d_in[7];
  const float* nw1  = (const float*)d_in[8];
  const float* nb1  = (const float*)d_in[9];
  const float* nw2  = (const float*)d_in[10];
  const float* nbng = (const float*)d_in[11];
  const float* nbnb = (const float*)d_in[12];
  const float* lproj  = (const float*)d_in[13];
  const float* lcoor  = (const float*)d_in[14];
  const float* lscale = (const float*)d_in[15];
  const float* lbng   = (const float*)d_in[16];
  const float* lbnb   = (const float*)d_in[17];
  const float* mw1  = (const float*)d_in[18];
  const float* mb1  = (const float*)d_in[19];
  const float* mw2  = (const float*)d_in[20];
  const float* mbng = (const float*)d_in[21];
  const float* mbnb = (const float*)d_in[22];
  const float* pg   = (const float*)d_in[23];
  const float* pb   = (const float*)d_in[24];
  const float* pw   = (const float*)d_in[25];
  float* out = (float*)d_out;

  // workspace (bytes)
  char* ws = (char*)d_ws;
  u16*   h_hi = (u16*)(ws + 0);              // 10,240,000
  u16*   h_lo = (u16*)(ws + 10240000);       // 10,240,000
  u16*   xp   = (u16*)(ws + 20480000);       // 10,240,000
  u16*   Wh   = (u16*)(ws + 61440000);       // 1,114,112
  u16*   Wl   = (u16*)(ws + 62554112);       // 1,114,112
  float* fb   = (float*)(ws + 63668224);     // 1,024

  const u16* nw1t   = Wh + 0;
  const u16* nw2t   = Wh + 32768;
  const u16* mw1t   = Wh + 65536;
  const u16* mw2t   = Wh + 262144;
  const u16* lprojt = Wh + 458752;
  const u16* postt  = Wh + 524288;
  const u16* nw1tl   = Wl + 0;
  const u16* nw2tl   = Wl + 32768;
  const u16* mw1tl   = Wl + 65536;
  const u16* mw2tl   = Wl + 262144;
  const u16* lprojtl = Wl + 458752;
  const u16* posttl  = Wl + 524288;

  prep_weights<<<2176, 256, 0, stream>>>(nw1, nw2, mw1, mw2, lproj, pw, pg, Wh, Wl);
  fold_pb<<<1, 256, 0, stream>>>(pw, pb, fb);

  spse_kernel<<<NPTS, 128, 0, stream>>>(x, xyz, knn, sm, scc, shh, bn0g, bn0b, h_hi, h_lo);

  // nbr_proj + nbr_bn: h = BN(gelu(nbr@w1+b1)@w2)
  mlp_fused<256, false><<<625, 512, 0, stream>>>(
      h_hi, h_lo, nw1t, nw1tl, nw2t, nw2tl, nb1, nbng, nbnb, h_hi, h_lo);
  // mlp 0 (residual)
  mlp_fused<512, true><<<625, 512, 0, stream>>>(
      h_hi, h_lo, mw1t, mw1tl, mw2t, mw2tl, mb1, mbng, mbnb, h_hi, h_lo);

  for (int i = 0; i < 4; i++) {
    k128_reg<0><<<dim3(625, 1), 256, 0, stream>>>(h_hi, h_lo, lprojt + i * 16384,
                                                  lprojtl + i * 16384, nullptr,
                                                  xp, nullptr, 128, 625);
    lfp_kernel<<<2500, 256, 0, stream>>>(xp, knn, xyz, lcoor + i * 96, lscale + i * 32,
                                         lbng + i * 128, lbnb + i * 128, h_hi, h_lo);
    if (i & 1) {
      const int j = i / 2 + 1;
      mlp_fused<512, true><<<625, 512, 0, stream>>>(
          h_hi, h_lo, mw1t + j * 65536, mw1tl + j * 65536, mw2t + j * 65536,
          mw2tl + j * 65536, mb1 + j * 512, mbng + j * 128, mbnb + j * 128, h_hi, h_lo);
    }
  }

  // postproj (BN folded into weights; rank-1 bias)
  k128_reg<2><<<dim3(256, 2), 256, 0, stream>>>(h_hi, h_lo, postt, posttl, fb,
                                                nullptr, out, 256, 625);
}

// Round 8
// 572.981 us; speedup vs baseline: 1.0818x; 1.0818x over previous
//
#include <hip/hip_runtime.h>
#include <hip/hip_bf16.h>
#include <math.h>

#define NPTS 40000
#define KNB 16
#define CH 128

typedef unsigned short u16;
typedef __attribute__((ext_vector_type(8))) short bf16x8;
typedef __attribute__((ext_vector_type(4))) float f32x4;

__device__ __forceinline__ float gelu_f(float v) {
  const float u = 0.7978845608028654f * (v + 0.044715f * v * v * v);
  const float t = __builtin_amdgcn_exp2f(-2.8853900817779268f * u);
  return v * __builtin_amdgcn_rcpf(1.0f + t);
}

__device__ __forceinline__ float bnscale(float g) {
  return g * rsqrtf(1.0f + 1e-5f);
}

__device__ __forceinline__ u16 f2bf(float x) {
  union { __hip_bfloat16 b; u16 u; } cv;
  cv.b = __float2bfloat16(x);
  return cv.u;
}

__device__ __forceinline__ float bf2f(u16 u) {
  union { float f; unsigned int i; } cv;
  cv.i = ((unsigned int)u) << 16;
  return cv.f;
}

__device__ __forceinline__ void bf16split(float x, u16& hi, u16& lo) {
  hi = f2bf(x);
  lo = f2bf(x - bf2f(hi));
}

// ---------------- knn_spse_4 + BN0 -> bf16 hi/lo ----------------
__global__ __launch_bounds__(128) void spse_kernel(
    const float* __restrict__ x, const float* __restrict__ xyz,
    const int* __restrict__ knn, const float* __restrict__ sm,
    const float* __restrict__ sc, const float* __restrict__ sh,
    const float* __restrict__ g0, const float* __restrict__ b0,
    u16* __restrict__ oh, u16* __restrict__ ol) {
  const int n = blockIdx.x;
  const int c = threadIdx.x;
  __shared__ float sr[KNB][3];
  __shared__ float sf[KNB][4];
  if (c < KNB) {
    const int j = knn[n * KNB + c];
    sr[c][0] = xyz[j * 3 + 0] - xyz[n * 3 + 0];
    sr[c][1] = xyz[j * 3 + 1] - xyz[n * 3 + 1];
    sr[c][2] = xyz[j * 3 + 2] - xyz[n * 3 + 2];
    float f0 = x[j * 4 + 0] - x[n * 4 + 0];
    float f1 = x[j * 4 + 1] - x[n * 4 + 1];
    float f2 = x[j * 4 + 2] - x[n * 4 + 2];
    float f3 = x[j * 4 + 3] - x[n * 4 + 3];
    sf[c][0] = f0 * f0; sf[c][1] = f1 * f1;
    sf[c][2] = f2 * f2; sf[c][3] = f3 * f3;
  }
  __syncthreads();
  const float m0 = sm[c], m1 = sm[CH + c], m2 = sm[2 * CH + c];
  const float m4 = sm[4 * CH + c], m5 = sm[5 * CH + c], m6 = sm[6 * CH + c];
  const float m8 = sm[8 * CH + c], m9 = sm[9 * CH + c], m10 = sm[10 * CH + c];
  float c0 = sc[c];          c0 *= c0;
  float c1 = sc[CH + c];     c1 *= c1;
  float c2 = sc[2 * CH + c]; c2 *= c2;
  float h2 = sh[c];          h2 *= h2;
  float e = 0.0f;
#pragma unroll
  for (int k = 0; k < KNB; k++) {
    const float r0 = sr[k][0], r1 = sr[k][1], r2 = sr[k][2];
    const float d0 = fmaf(r2, m2, fmaf(r1, m1, r0 * m0));
    const float d1 = fmaf(r2, m6, fmaf(r1, m5, r0 * m4));
    const float d2 = fmaf(r2, m10, fmaf(r1, m9, r0 * m8));
    e = fmaf(d0, d0, e);
    e = fmaf(d1, d1, e);
    e = fmaf(d2, d2, e);
    e = fmaf(sf[k][0], c0, e);
    e = fmaf(sf[k][1], c1, e);
    e = fmaf(sf[k][2], c2, e);
    e = fmaf(sf[k][3], h2, e);
  }
  const float v = sqrtf(e * (1.0f / KNB)) * bnscale(g0[c]) + b0[c];
  u16 hi, lo; bf16split(v, hi, lo);
  const size_t idx = (size_t)n * CH + c;
  oh[idx] = hi; ol[idx] = lo;
}

// ---------------- LFP gather + PE + max + BN + residual (h as hi/lo) ----------------
// 256 thr = 16 points, 16 lanes/point, 8 ch/lane, 16B bf16x8 gathers
__global__ __launch_bounds__(256) void lfp_kernel(
    const u16* __restrict__ xp, const int* __restrict__ knn,
    const float* __restrict__ xyz, const float* __restrict__ coor,
    const float* __restrict__ scale, const float* __restrict__ g,
    const float* __restrict__ b, u16* __restrict__ hh, u16* __restrict__ hl) {
  const int t = threadIdx.x;
  const int bid = blockIdx.x;
  __shared__ int si[16][KNB];
  __shared__ float sr[16][KNB][3];
  {
    const int pp = t >> 4, kk = t & 15;
    const int n = bid * 16 + pp;
    const int j = knn[n * KNB + kk];
    si[pp][kk] = j;
    sr[pp][kk][0] = xyz[j * 3 + 0] - xyz[n * 3 + 0];
    sr[pp][kk][1] = xyz[j * 3 + 1] - xyz[n * 3 + 1];
    sr[pp][kk][2] = xyz[j * 3 + 2] - xyz[n * 3 + 2];
  }
  __syncthreads();
  const int p = t >> 4, d8 = t & 15;   // channels c = d8*8 .. d8*8+7
  const int n = bid * 16 + p;
  const float c0a = coor[d8 * 2],     c1a = coor[32 + d8 * 2],     c2a = coor[64 + d8 * 2];
  const float c0b = coor[d8 * 2 + 1], c1b = coor[32 + d8 * 2 + 1], c2b = coor[64 + d8 * 2 + 1];
  float s2a = scale[d8 * 2];     s2a *= s2a;
  float s2b = scale[d8 * 2 + 1]; s2b *= s2b;
  float a[8];
#pragma unroll
  for (int e = 0; e < 8; e++) a[e] = -3.0e38f;
#pragma unroll
  for (int k = 0; k < KNB; k++) {
    const int j = si[p][k];
    const float r0 = sr[p][k][0], r1 = sr[p][k][1], r2 = sr[p][k][2];
    const float pea = fmaf(r2, c2a, fmaf(r1, c1a, r0 * c0a)) * s2a;
    const float peb = fmaf(r2, c2b, fmaf(r1, c1b, r0 * c0b)) * s2b;
    const bf16x8 v = *(const bf16x8*)(xp + (size_t)j * CH + d8 * 8);
#pragma unroll
    for (int e = 0; e < 4; e++) a[e] = fmaxf(a[e], bf2f((u16)v[e]) + pea);
#pragma unroll
    for (int e = 4; e < 8; e++) a[e] = fmaxf(a[e], bf2f((u16)v[e]) + peb);
  }
  const size_t off = (size_t)n * CH + d8 * 8;
  union { u16 a[8]; uint4 v; } ih, il, oh, ol;
  ih.v = *(const uint4*)(hh + off);
  il.v = *(const uint4*)(hl + off);
#pragma unroll
  for (int e = 0; e < 8; e++) {
    const int c = d8 * 8 + e;
    const float nv = bf2f(ih.a[e]) + bf2f(il.a[e]) + a[e] * bnscale(g[c]) + b[c];
    u16 hi, lo; bf16split(nv, hi, lo);
    oh.a[e] = hi; ol.a[e] = lo;
  }
  *(uint4*)(hh + off) = oh.v;
  *(uint4*)(hl + off) = ol.v;
}

// ---------------- weight prep: transpose + bf16 hi/lo (plain [n][k] layout) ----------
// dst (u16): nw1@0 [256][128], nw2@32768 [128][256], mw1[j]@65536+j*65536 [512][128],
// mw2[j]@262144+j*65536 [128][512], lproj[i]@458752+i*16384 [128][128], post@524288 [256][128]
__global__ __launch_bounds__(256) void prep_weights(
    const float* __restrict__ nw1, const float* __restrict__ nw2,
    const float* __restrict__ mw1, const float* __restrict__ mw2,
    const float* __restrict__ lproj, const float* __restrict__ pw,
    const float* __restrict__ pg, u16* __restrict__ th, u16* __restrict__ tl) {
  const int idx = blockIdx.x * 256 + threadIdx.x;
  const float* src;
  int local, Kd, Nd, dst;
  float scale = 1.0f;
  if (idx < 32768)        { src = nw1; local = idx;          Kd = 128; Nd = 256; dst = 0; }
  else if (idx < 65536)   { src = nw2; local = idx - 32768;  Kd = 256; Nd = 128; dst = 32768; }
  else if (idx < 262144)  { int j = (idx - 65536) >> 16;  local = (idx - 65536) & 65535;
                            src = mw1 + j * 65536; Kd = 128; Nd = 512; dst = 65536 + j * 65536; }
  else if (idx < 458752)  { int j = (idx - 262144) >> 16; local = (idx - 262144) & 65535;
                            src = mw2 + j * 65536; Kd = 512; Nd = 128; dst = 262144 + j * 65536; }
  else if (idx < 524288)  { int i = (idx - 458752) >> 14; local = (idx - 458752) & 16383;
                            src = lproj + i * 16384; Kd = 128; Nd = 128; dst = 458752 + i * 16384; }
  else if (idx < 557056)  { local = idx - 524288; src = pw; Kd = 128; Nd = 256; dst = 524288;
                            scale = bnscale(pg[local >> 8]); }
  else return;
  const int k = local / Nd, n = local % Nd;
  const float v = src[local] * scale;
  u16 hi, lo; bf16split(v, hi, lo);
  const int o = dst + n * Kd + k;
  th[o] = hi; tl[o] = lo;
}

// folded post bias: fb[n] = sum_k pb[k] * pw[k][n]
__global__ __launch_bounds__(256) void fold_pb(const float* __restrict__ pw,
                                               const float* __restrict__ pb,
                                               float* __restrict__ fb) {
  const int t = threadIdx.x;
  float a = 0.0f;
  for (int k = 0; k < 128; k++) a = fmaf(pb[k], pw[k * 256 + t], a);
  fb[t] = a;
}

// ---------------- barrier-free streaming K=128 GEMM, W in registers ----------------
// grid: x = row-tile slots (fast-varying; multiple of 8 when y>1), y = 128-col blocks.
// NSPLIT: 3 = Ahi*Bhi+Ahi*Blo+Alo*Bhi (exact-ish), 2 = Ahi*Bhi+Ahi*Blo (A-hi only).
// EPI: 0 -> bf16 store (xp); 1 -> gelu(v+bias) -> u16 act; 2 -> v+bias -> f32 out
template <int EPI, int NSPLIT>
__global__ __launch_bounds__(256, 2) void k128_reg(
    const u16* __restrict__ Ahi, const u16* __restrict__ Alo,
    const u16* __restrict__ Wth, const u16* __restrict__ Wtl,
    const float* __restrict__ p0, u16* __restrict__ outu,
    float* __restrict__ outf, int ostride, int ntiles) {
  const int t = threadIdx.x, lane = t & 63, w = t >> 6;
  const int col0 = blockIdx.y * 128;
  const int wm0 = (w >> 1) * 32, wn0 = (w & 1) * 64;
  const int lc = lane & 15, lq = lane >> 4;
  const int lq8 = lq * 8, lq4 = lq * 4;

  bf16x8 wh[4][4], wl[4][4];
  float bv[4];
#pragma unroll
  for (int nf = 0; nf < 4; nf++) {
    const int nr = col0 + wn0 + nf * 16 + lc;
    const u16* wr = Wth + (size_t)nr * 128;
    const u16* wr2 = Wtl + (size_t)nr * 128;
#pragma unroll
    for (int ks = 0; ks < 4; ks++) {
      wh[nf][ks] = *(const bf16x8*)(wr + ks * 32 + lq8);
      wl[nf][ks] = *(const bf16x8*)(wr2 + ks * 32 + lq8);
    }
    bv[nf] = (EPI == 0) ? 0.0f : p0[nr];
  }

  const f32x4 zz = {0.0f, 0.0f, 0.0f, 0.0f};
  for (int tile = blockIdx.x; tile < ntiles; tile += gridDim.x) {
    const int row0 = tile * 64;
    f32x4 acc[2][4];
#pragma unroll
    for (int mf = 0; mf < 2; mf++)
#pragma unroll
      for (int nf = 0; nf < 4; nf++) acc[mf][nf] = zz;
#pragma unroll
    for (int ks = 0; ks < 4; ks++) {
      bf16x8 ah[2], al[2];
#pragma unroll
      for (int mf = 0; mf < 2; mf++) {
        const size_t ao = (size_t)(row0 + wm0 + mf * 16 + lc) * 128 + ks * 32 + lq8;
        ah[mf] = *(const bf16x8*)(Ahi + ao);
        if (NSPLIT == 3) al[mf] = *(const bf16x8*)(Alo + ao);
      }
#pragma unroll
      for (int mf = 0; mf < 2; mf++)
#pragma unroll
        for (int nf = 0; nf < 4; nf++) {
          acc[mf][nf] = __builtin_amdgcn_mfma_f32_16x16x32_bf16(ah[mf], wh[nf][ks], acc[mf][nf], 0, 0, 0);
          acc[mf][nf] = __builtin_amdgcn_mfma_f32_16x16x32_bf16(ah[mf], wl[nf][ks], acc[mf][nf], 0, 0, 0);
          if (NSPLIT == 3)
            acc[mf][nf] = __builtin_amdgcn_mfma_f32_16x16x32_bf16(al[mf], wh[nf][ks], acc[mf][nf], 0, 0, 0);
        }
    }
#pragma unroll
    for (int mf = 0; mf < 2; mf++)
#pragma unroll
      for (int q = 0; q < 4; q++) {
        const int r = row0 + wm0 + mf * 16 + lq4 + q;
#pragma unroll
        for (int nf = 0; nf < 4; nf++) {
          const int col = col0 + wn0 + nf * 16 + lc;
          const size_t off = (size_t)r * ostride + col;
          const float v = acc[mf][nf][q];
          if (EPI == 0)      outu[off] = f2bf(v);
          else if (EPI == 1) outu[off] = f2bf(gelu_f(v + bv[nf]));
          else               outf[off] = v + bv[nf];
        }
      }
  }
}

// ---------------- w2 GEMM v4: barrier-free, LDS-free streaming ----------------
// h' = [h +] BN(act[M x K] @ W2[K x 128]); all operands straight global->reg.
// W2 hi/lo (<=256 KB) is L2-hot across 625 blocks. Full K unroll, no syncs:
// compiler pipelines the 10-load/16-MFMA iterations freely.
template <int K, bool RES>
__global__ __launch_bounds__(256, 2) void gemm_w2(
    const u16* __restrict__ A, const u16* __restrict__ Wth,
    const u16* __restrict__ Wtl, const float* __restrict__ g,
    const float* __restrict__ bb, u16* __restrict__ hh, u16* __restrict__ hl) {
  const int t = threadIdx.x, lane = t & 63, w = t >> 6;
  const int row0 = blockIdx.x * 64;
  const int wm0 = (w >> 1) * 32, wn0 = (w & 1) * 64;
  const int lc = lane & 15, lq = lane >> 4;
  const int lq8 = lq * 8, lq4 = lq * 4;

  const f32x4 zz = {0.0f, 0.0f, 0.0f, 0.0f};
  f32x4 acc[2][4];
#pragma unroll
  for (int mf = 0; mf < 2; mf++)
#pragma unroll
    for (int nf = 0; nf < 4; nf++) acc[mf][nf] = zz;

  const u16* arow0 = A + (size_t)(row0 + wm0 + lc) * K;
  const u16* arow1 = A + (size_t)(row0 + wm0 + 16 + lc) * K;

#pragma unroll
  for (int ks = 0; ks < K / 32; ks++) {
    const int e = ks * 32 + lq8;
    const bf16x8 af0 = *(const bf16x8*)(arow0 + e);
    const bf16x8 af1 = *(const bf16x8*)(arow1 + e);
    bf16x8 whf[4], wlf[4];
#pragma unroll
    for (int nf = 0; nf < 4; nf++) {
      const size_t wo = (size_t)(wn0 + nf * 16 + lc) * K + e;
      whf[nf] = *(const bf16x8*)(Wth + wo);
      wlf[nf] = *(const bf16x8*)(Wtl + wo);
    }
#pragma unroll
    for (int nf = 0; nf < 4; nf++) {
      acc[0][nf] = __builtin_amdgcn_mfma_f32_16x16x32_bf16(af0, whf[nf], acc[0][nf], 0, 0, 0);
      acc[0][nf] = __builtin_amdgcn_mfma_f32_16x16x32_bf16(af0, wlf[nf], acc[0][nf], 0, 0, 0);
      acc[1][nf] = __builtin_amdgcn_mfma_f32_16x16x32_bf16(af1, whf[nf], acc[1][nf], 0, 0, 0);
      acc[1][nf] = __builtin_amdgcn_mfma_f32_16x16x32_bf16(af1, wlf[nf], acc[1][nf], 0, 0, 0);
    }
  }

  float S0[4], S1[4];
#pragma unroll
  for (int nf = 0; nf < 4; nf++) {
    const int col = wn0 + nf * 16 + lc;
    S0[nf] = bnscale(g[col]);
    S1[nf] = bb[col];
  }
#pragma unroll
  for (int mf = 0; mf < 2; mf++)
#pragma unroll
    for (int q = 0; q < 4; q++) {
      const int r = row0 + wm0 + mf * 16 + lq4 + q;
#pragma unroll
      for (int nf = 0; nf < 4; nf++) {
        const int col = wn0 + nf * 16 + lc;
        const size_t off = (size_t)r * CH + col;
        float v = acc[mf][nf][q] * S0[nf] + S1[nf];
        if (RES) v += bf2f(hh[off]) + bf2f(hl[off]);
        u16 hi, lo; bf16split(v, hi, lo);
        hh[off] = hi; hl[off] = lo;
      }
    }
}

extern "C" void kernel_launch(void* const* d_in, const int* in_sizes, int n_in,
                              void* d_out, int out_size, void* d_ws, size_t ws_size,
                              hipStream_t stream) {
  const float* x    = (const float*)d_in[0];
  const float* xyz  = (const float*)d_in[1];
  const int*   knn  = (const int*)d_in[2];
  const float* sm   = (const float*)d_in[3];
  const float* scc  = (const float*)d_in[4];
  const float* shh  = (const float*)d_in[5];
  const float* bn0g = (const float*)d_in[6];
  const float* bn0b = (const float*)d_in[7];
  const float* nw1  = (const float*)d_in[8];
  const float* nb1  = (const float*)d_in[9];
  const float* nw2  = (const float*)d_in[10];
  const float* nbng = (const float*)d_in[11];
  const float* nbnb = (const float*)d_in[12];
  const float* lproj  = (const float*)d_in[13];
  const float* lcoor  = (const float*)d_in[14];
  const float* lscale = (const float*)d_in[15];
  const float* lbng   = (const float*)d_in[16];
  const float* lbnb   = (const float*)d_in[17];
  const float* mw1  = (const float*)d_in[18];
  const float* mb1  = (const float*)d_in[19];
  const float* mw2  = (const float*)d_in[20];
  const float* mbng = (const float*)d_in[21];
  const float* mbnb = (const float*)d_in[22];
  const float* pg   = (const float*)d_in[23];
  const float* pb   = (const float*)d_in[24];
  const float* pw   = (const float*)d_in[25];
  float* out = (float*)d_out;

  // workspace (bytes)
  char* ws = (char*)d_ws;
  u16*   h_hi = (u16*)(ws + 0);              // 10,240,000
  u16*   h_lo = (u16*)(ws + 10240000);       // 10,240,000
  u16*   act  = (u16*)(ws + 20480000);       // 40,960,000 (40000x512 bf16-hi)
  u16*   xp   = (u16*)(ws + 20480000);       // 10,240,000 (aliases act; never co-live)
  u16*   Wh   = (u16*)(ws + 61440000);       // 1,114,112
  u16*   Wl   = (u16*)(ws + 62554112);       // 1,114,112
  float* fb   = (float*)(ws + 63668224);     // 1,024

  const u16* nw1t   = Wh + 0;
  const u16* nw2t   = Wh + 32768;
  const u16* mw1t   = Wh + 65536;
  const u16* mw2t   = Wh + 262144;
  const u16* lprojt = Wh + 458752;
  const u16* postt  = Wh + 524288;
  const u16* nw1tl   = Wl + 0;
  const u16* nw2tl   = Wl + 32768;
  const u16* mw1tl   = Wl + 65536;
  const u16* mw2tl   = Wl + 262144;
  const u16* lprojtl = Wl + 458752;
  const u16* posttl  = Wl + 524288;

  prep_weights<<<2176, 256, 0, stream>>>(nw1, nw2, mw1, mw2, lproj, pw, pg, Wh, Wl);
  fold_pb<<<1, 256, 0, stream>>>(pw, pb, fb);

  spse_kernel<<<NPTS, 128, 0, stream>>>(x, xyz, knn, sm, scc, shh, bn0g, bn0b, h_hi, h_lo);

  // nbr_proj: act = gelu(nbr@w1+b1); h = BN(act@w2)
  k128_reg<1, 2><<<dim3(256, 2), 256, 0, stream>>>(h_hi, h_lo, nw1t, nw1tl, nb1,
                                                   act, nullptr, 256, 625);
  gemm_w2<256, false><<<625, 256, 0, stream>>>(act, nw2t, nw2tl, nbng, nbnb, h_hi, h_lo);

  // mlp 0 (residual)
  k128_reg<1, 2><<<dim3(128, 4), 256, 0, stream>>>(h_hi, h_lo, mw1t, mw1tl, mb1,
                                                   act, nullptr, 512, 625);
  gemm_w2<512, true><<<625, 256, 0, stream>>>(act, mw2t, mw2tl, mbng, mbnb, h_hi, h_lo);

  for (int i = 0; i < 4; i++) {
    k128_reg<0, 2><<<dim3(625, 1), 256, 0, stream>>>(h_hi, h_lo, lprojt + i * 16384,
                                                     lprojtl + i * 16384, nullptr,
                                                     xp, nullptr, 128, 625);
    lfp_kernel<<<2500, 256, 0, stream>>>(xp, knn, xyz, lcoor + i * 96, lscale + i * 32,
                                         lbng + i * 128, lbnb + i * 128, h_hi, h_lo);
    if (i & 1) {
      const int j = i / 2 + 1;
      k128_reg<1, 2><<<dim3(128, 4), 256, 0, stream>>>(h_hi, h_lo, mw1t + j * 65536,
                                                       mw1tl + j * 65536, mb1 + j * 512,
                                                       act, nullptr, 512, 625);
      gemm_w2<512, true><<<625, 256, 0, stream>>>(act, mw2t + j * 65536, mw2tl + j * 65536,
                                                  mbng + j * 128, mbnb + j * 128,
                                                  h_hi, h_lo);
    }
  }

  // postproj (BN folded into weights; rank-1 bias) — exact 3-split
  k128_reg<2, 3><<<dim3(256, 2), 256, 0, stream>>>(h_hi, h_lo, postt, posttl, fb,
                                                   nullptr, out, 256, 625);
}

// Round 9
// 462.945 us; speedup vs baseline: 1.3390x; 1.2377x over previous
//
#include <hip/hip_runtime.h>
#include <hip/hip_bf16.h>
#include <math.h>

#define NPTS 40000
#define KNB 16
#define CH 128

typedef unsigned short u16;
typedef __attribute__((ext_vector_type(8))) short bf16x8;
typedef __attribute__((ext_vector_type(4))) float f32x4;

__device__ __forceinline__ float gelu_f(float v) {
  const float u = 0.7978845608028654f * (v + 0.044715f * v * v * v);
  const float t = __builtin_amdgcn_exp2f(-2.8853900817779268f * u);
  return v * __builtin_amdgcn_rcpf(1.0f + t);
}

__device__ __forceinline__ float bnscale(float g) {
  return g * rsqrtf(1.0f + 1e-5f);
}

__device__ __forceinline__ u16 f2bf(float x) {
  union { __hip_bfloat16 b; u16 u; } cv;
  cv.b = __float2bfloat16(x);
  return cv.u;
}

__device__ __forceinline__ float bf2f(u16 u) {
  union { float f; unsigned int i; } cv;
  cv.i = ((unsigned int)u) << 16;
  return cv.f;
}

__device__ __forceinline__ void bf16split(float x, u16& hi, u16& lo) {
  hi = f2bf(x);
  lo = f2bf(x - bf2f(hi));
}

// async global->LDS: 16B/lane, wave-uniform LDS base + lane*16
__device__ __forceinline__ void gl2lds(const u16* gp, u16* lp) {
  __builtin_amdgcn_global_load_lds(
      (const __attribute__((address_space(1))) void*)gp,
      (__attribute__((address_space(3))) void*)lp, 16, 0, 0);
}

// ---------------- knn_spse_4 + BN0 -> bf16 hi/lo ----------------
__global__ __launch_bounds__(128) void spse_kernel(
    const float* __restrict__ x, const float* __restrict__ xyz,
    const int* __restrict__ knn, const float* __restrict__ sm,
    const float* __restrict__ sc, const float* __restrict__ sh,
    const float* __restrict__ g0, const float* __restrict__ b0,
    u16* __restrict__ oh, u16* __restrict__ ol) {
  const int n = blockIdx.x;
  const int c = threadIdx.x;
  __shared__ float sr[KNB][3];
  __shared__ float sf[KNB][4];
  if (c < KNB) {
    const int j = knn[n * KNB + c];
    sr[c][0] = xyz[j * 3 + 0] - xyz[n * 3 + 0];
    sr[c][1] = xyz[j * 3 + 1] - xyz[n * 3 + 1];
    sr[c][2] = xyz[j * 3 + 2] - xyz[n * 3 + 2];
    float f0 = x[j * 4 + 0] - x[n * 4 + 0];
    float f1 = x[j * 4 + 1] - x[n * 4 + 1];
    float f2 = x[j * 4 + 2] - x[n * 4 + 2];
    float f3 = x[j * 4 + 3] - x[n * 4 + 3];
    sf[c][0] = f0 * f0; sf[c][1] = f1 * f1;
    sf[c][2] = f2 * f2; sf[c][3] = f3 * f3;
  }
  __syncthreads();
  const float m0 = sm[c], m1 = sm[CH + c], m2 = sm[2 * CH + c];
  const float m4 = sm[4 * CH + c], m5 = sm[5 * CH + c], m6 = sm[6 * CH + c];
  const float m8 = sm[8 * CH + c], m9 = sm[9 * CH + c], m10 = sm[10 * CH + c];
  float c0 = sc[c];          c0 *= c0;
  float c1 = sc[CH + c];     c1 *= c1;
  float c2 = sc[2 * CH + c]; c2 *= c2;
  float h2 = sh[c];          h2 *= h2;
  float e = 0.0f;
#pragma unroll
  for (int k = 0; k < KNB; k++) {
    const float r0 = sr[k][0], r1 = sr[k][1], r2 = sr[k][2];
    const float d0 = fmaf(r2, m2, fmaf(r1, m1, r0 * m0));
    const float d1 = fmaf(r2, m6, fmaf(r1, m5, r0 * m4));
    const float d2 = fmaf(r2, m10, fmaf(r1, m9, r0 * m8));
    e = fmaf(d0, d0, e);
    e = fmaf(d1, d1, e);
    e = fmaf(d2, d2, e);
    e = fmaf(sf[k][0], c0, e);
    e = fmaf(sf[k][1], c1, e);
    e = fmaf(sf[k][2], c2, e);
    e = fmaf(sf[k][3], h2, e);
  }
  const float v = sqrtf(e * (1.0f / KNB)) * bnscale(g0[c]) + b0[c];
  u16 hi, lo; bf16split(v, hi, lo);
  const size_t idx = (size_t)n * CH + c;
  oh[idx] = hi; ol[idx] = lo;
}

// ---------------- LFP gather + PE + max + BN + residual (h as hi/lo) ----------------
// 256 thr = 16 points, 16 lanes/point, 8 ch/lane, 16B bf16x8 gathers
__global__ __launch_bounds__(256) void lfp_kernel(
    const u16* __restrict__ xp, const int* __restrict__ knn,
    const float* __restrict__ xyz, const float* __restrict__ coor,
    const float* __restrict__ scale, const float* __restrict__ g,
    const float* __restrict__ b, u16* __restrict__ hh, u16* __restrict__ hl) {
  const int t = threadIdx.x;
  const int bid = blockIdx.x;
  __shared__ int si[16][KNB];
  __shared__ float sr[16][KNB][3];
  {
    const int pp = t >> 4, kk = t & 15;
    const int n = bid * 16 + pp;
    const int j = knn[n * KNB + kk];
    si[pp][kk] = j;
    sr[pp][kk][0] = xyz[j * 3 + 0] - xyz[n * 3 + 0];
    sr[pp][kk][1] = xyz[j * 3 + 1] - xyz[n * 3 + 1];
    sr[pp][kk][2] = xyz[j * 3 + 2] - xyz[n * 3 + 2];
  }
  __syncthreads();
  const int p = t >> 4, d8 = t & 15;   // channels c = d8*8 .. d8*8+7
  const int n = bid * 16 + p;
  const float c0a = coor[d8 * 2],     c1a = coor[32 + d8 * 2],     c2a = coor[64 + d8 * 2];
  const float c0b = coor[d8 * 2 + 1], c1b = coor[32 + d8 * 2 + 1], c2b = coor[64 + d8 * 2 + 1];
  float s2a = scale[d8 * 2];     s2a *= s2a;
  float s2b = scale[d8 * 2 + 1]; s2b *= s2b;
  float a[8];
#pragma unroll
  for (int e = 0; e < 8; e++) a[e] = -3.0e38f;
#pragma unroll
  for (int k = 0; k < KNB; k++) {
    const int j = si[p][k];
    const float r0 = sr[p][k][0], r1 = sr[p][k][1], r2 = sr[p][k][2];
    const float pea = fmaf(r2, c2a, fmaf(r1, c1a, r0 * c0a)) * s2a;
    const float peb = fmaf(r2, c2b, fmaf(r1, c1b, r0 * c0b)) * s2b;
    const bf16x8 v = *(const bf16x8*)(xp + (size_t)j * CH + d8 * 8);
#pragma unroll
    for (int e = 0; e < 4; e++) a[e] = fmaxf(a[e], bf2f((u16)v[e]) + pea);
#pragma unroll
    for (int e = 4; e < 8; e++) a[e] = fmaxf(a[e], bf2f((u16)v[e]) + peb);
  }
  const size_t off = (size_t)n * CH + d8 * 8;
  union { u16 a[8]; uint4 v; } ih, il, oh, ol;
  ih.v = *(const uint4*)(hh + off);
  il.v = *(const uint4*)(hl + off);
#pragma unroll
  for (int e = 0; e < 8; e++) {
    const int c = d8 * 8 + e;
    const float nv = bf2f(ih.a[e]) + bf2f(il.a[e]) + a[e] * bnscale(g[c]) + b[c];
    u16 hi, lo; bf16split(nv, hi, lo);
    oh.a[e] = hi; ol.a[e] = lo;
  }
  *(uint4*)(hh + off) = oh.v;
  *(uint4*)(hl + off) = ol.v;
}

// ---------------- weight prep: transpose + bf16 hi/lo (+64-window swizzle for w2) ----
__global__ __launch_bounds__(256) void prep_weights(
    const float* __restrict__ nw1, const float* __restrict__ nw2,
    const float* __restrict__ mw1, const float* __restrict__ mw2,
    const float* __restrict__ lproj, const float* __restrict__ pw,
    const float* __restrict__ pg, u16* __restrict__ th, u16* __restrict__ tl) {
  const int idx = blockIdx.x * 256 + threadIdx.x;
  const float* src;
  int local, Kd, Nd, dst, swz;
  float scale = 1.0f;
  if (idx < 32768)        { src = nw1; local = idx;          Kd = 128; Nd = 256; dst = 0; swz = 0; }
  else if (idx < 65536)   { src = nw2; local = idx - 32768;  Kd = 256; Nd = 128; dst = 32768; swz = 1; }
  else if (idx < 262144)  { int j = (idx - 65536) >> 16;  local = (idx - 65536) & 65535;
                            src = mw1 + j * 65536; Kd = 128; Nd = 512; dst = 65536 + j * 65536; swz = 0; }
  else if (idx < 458752)  { int j = (idx - 262144) >> 16; local = (idx - 262144) & 65535;
                            src = mw2 + j * 65536; Kd = 512; Nd = 128; dst = 262144 + j * 65536; swz = 1; }
  else if (idx < 524288)  { int i = (idx - 458752) >> 14; local = (idx - 458752) & 16383;
                            src = lproj + i * 16384; Kd = 128; Nd = 128; dst = 458752 + i * 16384; swz = 0; }
  else if (idx < 557056)  { local = idx - 524288; src = pw; Kd = 128; Nd = 256; dst = 524288; swz = 0;
                            scale = bnscale(pg[local >> 8]); }
  else return;
  const int k = local / Nd, n = local % Nd;
  const float v = src[local] * scale;
  u16 hi, lo; bf16split(v, hi, lo);
  const int ks = swz ? ((k & ~63) | ((k & 63) ^ ((n & 7) << 3))) : k;
  const int o = dst + n * Kd + ks;
  th[o] = hi; tl[o] = lo;
}

// folded post bias: fb[n] = sum_k pb[k] * pw[k][n]
__global__ __launch_bounds__(256) void fold_pb(const float* __restrict__ pw,
                                               const float* __restrict__ pb,
                                               float* __restrict__ fb) {
  const int t = threadIdx.x;
  float a = 0.0f;
  for (int k = 0; k < 128; k++) a = fmaf(pb[k], pw[k * 256 + t], a);
  fb[t] = a;
}

// ---------------- barrier-free streaming K=128 GEMM, W in registers ----------------
// NSPLIT: 3 = Ahi*Bhi+Ahi*Blo+Alo*Bhi (exact-ish), 2 = Ahi*Bhi+Ahi*Blo (A-hi only).
// EPI: 0 -> bf16 store (xp); 1 -> gelu(v+bias) -> u16 act; 2 -> v+bias -> f32 out
template <int EPI, int NSPLIT>
__global__ __launch_bounds__(256, 2) void k128_reg(
    const u16* __restrict__ Ahi, const u16* __restrict__ Alo,
    const u16* __restrict__ Wth, const u16* __restrict__ Wtl,
    const float* __restrict__ p0, u16* __restrict__ outu,
    float* __restrict__ outf, int ostride, int ntiles) {
  const int t = threadIdx.x, lane = t & 63, w = t >> 6;
  const int col0 = blockIdx.y * 128;
  const int wm0 = (w >> 1) * 32, wn0 = (w & 1) * 64;
  const int lc = lane & 15, lq = lane >> 4;
  const int lq8 = lq * 8, lq4 = lq * 4;

  bf16x8 wh[4][4], wl[4][4];
  float bv[4];
#pragma unroll
  for (int nf = 0; nf < 4; nf++) {
    const int nr = col0 + wn0 + nf * 16 + lc;
    const u16* wr = Wth + (size_t)nr * 128;
    const u16* wr2 = Wtl + (size_t)nr * 128;
#pragma unroll
    for (int ks = 0; ks < 4; ks++) {
      wh[nf][ks] = *(const bf16x8*)(wr + ks * 32 + lq8);
      wl[nf][ks] = *(const bf16x8*)(wr2 + ks * 32 + lq8);
    }
    bv[nf] = (EPI == 0) ? 0.0f : p0[nr];
  }

  const f32x4 zz = {0.0f, 0.0f, 0.0f, 0.0f};
  for (int tile = blockIdx.x; tile < ntiles; tile += gridDim.x) {
    const int row0 = tile * 64;
    f32x4 acc[2][4];
#pragma unroll
    for (int mf = 0; mf < 2; mf++)
#pragma unroll
      for (int nf = 0; nf < 4; nf++) acc[mf][nf] = zz;
#pragma unroll
    for (int ks = 0; ks < 4; ks++) {
      bf16x8 ah[2], al[2];
#pragma unroll
      for (int mf = 0; mf < 2; mf++) {
        const size_t ao = (size_t)(row0 + wm0 + mf * 16 + lc) * 128 + ks * 32 + lq8;
        ah[mf] = *(const bf16x8*)(Ahi + ao);
        if (NSPLIT == 3) al[mf] = *(const bf16x8*)(Alo + ao);
      }
#pragma unroll
      for (int mf = 0; mf < 2; mf++)
#pragma unroll
        for (int nf = 0; nf < 4; nf++) {
          acc[mf][nf] = __builtin_amdgcn_mfma_f32_16x16x32_bf16(ah[mf], wh[nf][ks], acc[mf][nf], 0, 0, 0);
          acc[mf][nf] = __builtin_amdgcn_mfma_f32_16x16x32_bf16(ah[mf], wl[nf][ks], acc[mf][nf], 0, 0, 0);
          if (NSPLIT == 3)
            acc[mf][nf] = __builtin_amdgcn_mfma_f32_16x16x32_bf16(al[mf], wh[nf][ks], acc[mf][nf], 0, 0, 0);
        }
    }
#pragma unroll
    for (int mf = 0; mf < 2; mf++)
#pragma unroll
      for (int q = 0; q < 4; q++) {
        const int r = row0 + wm0 + mf * 16 + lq4 + q;
#pragma unroll
        for (int nf = 0; nf < 4; nf++) {
          const int col = col0 + wn0 + nf * 16 + lc;
          const size_t off = (size_t)r * ostride + col;
          const float v = acc[mf][nf][q];
          if (EPI == 0)      outu[off] = f2bf(v);
          else if (EPI == 1) outu[off] = f2bf(gelu_f(v + bv[nf]));
          else               outf[off] = v + bv[nf];
        }
      }
  }
}

// ---------------- w2 GEMM v3 (round-6 proven): LDS dbuf BK=64 + reg prefetch --------
// h' = [h +] BN(act[M x K] @ W2[K x 128]); BM=64 (625 exact blocks), all 128 cols.
// W2-hi double-buffered in LDS (16 KB/buf, 64-window XOR swizzle); W2-lo direct
// from L2-hot global; act frags global->reg prefetched 1 slab ahead. 1 barrier/iter.
template <int K, bool RES>
__global__ __launch_bounds__(256, 3) void gemm_w2(
    const u16* __restrict__ A, const u16* __restrict__ Wth,
    const u16* __restrict__ Wtl, const float* __restrict__ g,
    const float* __restrict__ bb, u16* __restrict__ hh, u16* __restrict__ hl) {
  __shared__ __align__(16) u16 Ws[2][128 * 64];   // [buf][n=128][k=64]
  const int t = threadIdx.x, lane = t & 63, w = t >> 6;
  const int row0 = blockIdx.x * 64;
  const int wm0 = (w >> 1) * 32, wn0 = (w & 1) * 64;
  const int lc = lane & 15, lq = lane >> 4;
  const int lq8 = lq * 8, lq4 = lq * 4;

  const f32x4 zz = {0.0f, 0.0f, 0.0f, 0.0f};
  f32x4 acc[2][4];
#pragma unroll
  for (int mf = 0; mf < 2; mf++)
#pragma unroll
    for (int nf = 0; nf < 4; nf++) acc[mf][nf] = zz;

  auto stage_slab = [&](u16* lds, int kb) {
#pragma unroll
    for (int i = 0; i < 1024; i += 256) {       // 1024 chunks of 16B
      const int wc0 = i + w * 64;
      const int c = wc0 + lane;
      gl2lds(Wth + (size_t)(c >> 3) * K + kb + (c & 7) * 8, lds + wc0 * 8);
    }
  };
  auto load_af = [&](bf16x8 (&dst)[2][2], int kb) {
#pragma unroll
    for (int mf = 0; mf < 2; mf++)
#pragma unroll
      for (int ks = 0; ks < 2; ks++)
        dst[mf][ks] = *(const bf16x8*)(A + (size_t)(row0 + wm0 + mf * 16 + lc) * K +
                                       kb + ks * 32 + lq8);
  };

  bf16x8 afc[2][2], afn[2][2];
  stage_slab(Ws[0], 0);
  load_af(afc, 0);
  __syncthreads();

  constexpr int NT = K / 64;
#pragma unroll 2
  for (int tt = 0; tt < NT; tt++) {
    const int cur = tt & 1;
    if (tt + 1 < NT) {
      stage_slab(Ws[cur ^ 1], (tt + 1) * 64);   // async, flies under MFMA
      load_af(afn, (tt + 1) * 64);              // reg prefetch
    }
#pragma unroll
    for (int ks = 0; ks < 2; ks++) {
      bf16x8 whf[4], wlf[4];
#pragma unroll
      for (int nf = 0; nf < 4; nf++) {
        const int nr = wn0 + nf * 16 + lc;
        const int j = (ks * 32 + lq8) ^ ((nr & 7) << 3);
        whf[nf] = *(const bf16x8*)(Ws[cur] + nr * 64 + j);
        wlf[nf] = *(const bf16x8*)(Wtl + (size_t)nr * K + tt * 64 + j);
      }
#pragma unroll
      for (int mf = 0; mf < 2; mf++)
#pragma unroll
        for (int nf = 0; nf < 4; nf++) {
          acc[mf][nf] = __builtin_amdgcn_mfma_f32_16x16x32_bf16(afc[mf][ks], whf[nf], acc[mf][nf], 0, 0, 0);
          acc[mf][nf] = __builtin_amdgcn_mfma_f32_16x16x32_bf16(afc[mf][ks], wlf[nf], acc[mf][nf], 0, 0, 0);
        }
    }
    __syncthreads();   // drains next-slab stage; guards buf reuse
#pragma unroll
    for (int mf = 0; mf < 2; mf++)
#pragma unroll
      for (int ks = 0; ks < 2; ks++) afc[mf][ks] = afn[mf][ks];
  }

  float S0[4], S1[4];
#pragma unroll
  for (int nf = 0; nf < 4; nf++) {
    const int col = wn0 + nf * 16 + lc;
    S0[nf] = bnscale(g[col]);
    S1[nf] = bb[col];
  }
#pragma unroll
  for (int mf = 0; mf < 2; mf++)
#pragma unroll
    for (int q = 0; q < 4; q++) {
      const int r = row0 + wm0 + mf * 16 + lq4 + q;
#pragma unroll
      for (int nf = 0; nf < 4; nf++) {
        const int col = wn0 + nf * 16 + lc;
        const size_t off = (size_t)r * CH + col;
        float v = acc[mf][nf][q] * S0[nf] + S1[nf];
        if (RES) v += bf2f(hh[off]) + bf2f(hl[off]);
        u16 hi, lo; bf16split(v, hi, lo);
        hh[off] = hi; hl[off] = lo;
      }
    }
}

extern "C" void kernel_launch(void* const* d_in, const int* in_sizes, int n_in,
                              void* d_out, int out_size, void* d_ws, size_t ws_size,
                              hipStream_t stream) {
  const float* x    = (const float*)d_in[0];
  const float* xyz  = (const float*)d_in[1];
  const int*   knn  = (const int*)d_in[2];
  const float* sm   = (const float*)d_in[3];
  const float* scc  = (const float*)d_in[4];
  const float* shh  = (const float*)d_in[5];
  const float* bn0g = (const float*)d_in[6];
  const float* bn0b = (const float*)d_in[7];
  const float* nw1  = (const float*)d_in[8];
  const float* nb1  = (const float*)d_in[9];
  const float* nw2  = (const float*)d_in[10];
  const float* nbng = (const float*)d_in[11];
  const float* nbnb = (const float*)d_in[12];
  const float* lproj  = (const float*)d_in[13];
  const float* lcoor  = (const float*)d_in[14];
  const float* lscale = (const float*)d_in[15];
  const float* lbng   = (const float*)d_in[16];
  const float* lbnb   = (const float*)d_in[17];
  const float* mw1  = (const float*)d_in[18];
  const float* mb1  = (const float*)d_in[19];
  const float* mw2  = (const float*)d_in[20];
  const float* mbng = (const float*)d_in[21];
  const float* mbnb = (const float*)d_in[22];
  const float* pg   = (const float*)d_in[23];
  const float* pb   = (const float*)d_in[24];
  const float* pw   = (const float*)d_in[25];
  float* out = (float*)d_out;

  // workspace (bytes)
  char* ws = (char*)d_ws;
  u16*   h_hi = (u16*)(ws + 0);              // 10,240,000
  u16*   h_lo = (u16*)(ws + 10240000);       // 10,240,000
  u16*   act  = (u16*)(ws + 20480000);       // 40,960,000 (40000x512 bf16-hi)
  u16*   xp   = (u16*)(ws + 20480000);       // 10,240,000 (aliases act; never co-live)
  u16*   Wh   = (u16*)(ws + 61440000);       // 1,114,112
  u16*   Wl   = (u16*)(ws + 62554112);       // 1,114,112
  float* fb   = (float*)(ws + 63668224);     // 1,024

  const u16* nw1t   = Wh + 0;
  const u16* nw2t   = Wh + 32768;
  const u16* mw1t   = Wh + 65536;
  const u16* mw2t   = Wh + 262144;
  const u16* lprojt = Wh + 458752;
  const u16* postt  = Wh + 524288;
  const u16* nw1tl   = Wl + 0;
  const u16* nw2tl   = Wl + 32768;
  const u16* mw1tl   = Wl + 65536;
  const u16* mw2tl   = Wl + 262144;
  const u16* lprojtl = Wl + 458752;
  const u16* posttl  = Wl + 524288;

  prep_weights<<<2176, 256, 0, stream>>>(nw1, nw2, mw1, mw2, lproj, pw, pg, Wh, Wl);
  fold_pb<<<1, 256, 0, stream>>>(pw, pb, fb);

  spse_kernel<<<NPTS, 128, 0, stream>>>(x, xyz, knn, sm, scc, shh, bn0g, bn0b, h_hi, h_lo);

  // nbr_proj: act = gelu(nbr@w1+b1); h = BN(act@w2)
  k128_reg<1, 2><<<dim3(256, 2), 256, 0, stream>>>(h_hi, h_lo, nw1t, nw1tl, nb1,
                                                   act, nullptr, 256, 625);
  gemm_w2<256, false><<<625, 256, 0, stream>>>(act, nw2t, nw2tl, nbng, nbnb, h_hi, h_lo);

  // mlp 0 (residual)
  k128_reg<1, 2><<<dim3(128, 4), 256, 0, stream>>>(h_hi, h_lo, mw1t, mw1tl, mb1,
                                                   act, nullptr, 512, 625);
  gemm_w2<512, true><<<625, 256, 0, stream>>>(act, mw2t, mw2tl, mbng, mbnb, h_hi, h_lo);

  for (int i = 0; i < 4; i++) {
    k128_reg<0, 2><<<dim3(625, 1), 256, 0, stream>>>(h_hi, h_lo, lprojt + i * 16384,
                                                     lprojtl + i * 16384, nullptr,
                                                     xp, nullptr, 128, 625);
    lfp_kernel<<<2500, 256, 0, stream>>>(xp, knn, xyz, lcoor + i * 96, lscale + i * 32,
                                         lbng + i * 128, lbnb + i * 128, h_hi, h_lo);
    if (i & 1) {
      const int j = i / 2 + 1;
      k128_reg<1, 2><<<dim3(128, 4), 256, 0, stream>>>(h_hi, h_lo, mw1t + j * 65536,
                                                       mw1tl + j * 65536, mb1 + j * 512,
                                                       act, nullptr, 512, 625);
      gemm_w2<512, true><<<625, 256, 0, stream>>>(act, mw2t + j * 65536, mw2tl + j * 65536,
                                                  mbng + j * 128, mbnb + j * 128,
                                                  h_hi, h_lo);
    }
  }

  // postproj (BN folded into weights; rank-1 bias) — exact 3-split
  k128_reg<2, 3><<<dim3(256, 2), 256, 0, stream>>>(h_hi, h_lo, postt, posttl, fb,
                                                   nullptr, out, 256, 625);
}

// Round 10
// 425.274 us; speedup vs baseline: 1.4576x; 1.0886x over previous
//
#include <hip/hip_runtime.h>
#include <hip/hip_bf16.h>
#include <math.h>

#define NPTS 40000
#define KNB 16
#define CH 128

typedef unsigned short u16;
typedef __attribute__((ext_vector_type(8))) short bf16x8;
typedef __attribute__((ext_vector_type(4))) float f32x4;

__device__ __forceinline__ float gelu_f(float v) {
  const float u = 0.7978845608028654f * (v + 0.044715f * v * v * v);
  const float t = __builtin_amdgcn_exp2f(-2.8853900817779268f * u);
  return v * __builtin_amdgcn_rcpf(1.0f + t);
}

__device__ __forceinline__ float bnscale(float g) {
  return g * rsqrtf(1.0f + 1e-5f);
}

__device__ __forceinline__ u16 f2bf(float x) {
  union { __hip_bfloat16 b; u16 u; } cv;
  cv.b = __float2bfloat16(x);
  return cv.u;
}

__device__ __forceinline__ float bf2f(u16 u) {
  union { float f; unsigned int i; } cv;
  cv.i = ((unsigned int)u) << 16;
  return cv.f;
}

__device__ __forceinline__ void bf16split(float x, u16& hi, u16& lo) {
  hi = f2bf(x);
  lo = f2bf(x - bf2f(hi));
}

// async global->LDS: 16B/lane, wave-uniform LDS base + lane*16
__device__ __forceinline__ void gl2lds(const u16* gp, u16* lp) {
  __builtin_amdgcn_global_load_lds(
      (const __attribute__((address_space(1))) void*)gp,
      (__attribute__((address_space(3))) void*)lp, 16, 0, 0);
}

// ---------------- knn_spse_4 + BN0 -> bf16 hi/lo ----------------
__global__ __launch_bounds__(128) void spse_kernel(
    const float* __restrict__ x, const float* __restrict__ xyz,
    const int* __restrict__ knn, const float* __restrict__ sm,
    const float* __restrict__ sc, const float* __restrict__ sh,
    const float* __restrict__ g0, const float* __restrict__ b0,
    u16* __restrict__ oh, u16* __restrict__ ol) {
  const int n = blockIdx.x;
  const int c = threadIdx.x;
  __shared__ float sr[KNB][3];
  __shared__ float sf[KNB][4];
  if (c < KNB) {
    const int j = knn[n * KNB + c];
    sr[c][0] = xyz[j * 3 + 0] - xyz[n * 3 + 0];
    sr[c][1] = xyz[j * 3 + 1] - xyz[n * 3 + 1];
    sr[c][2] = xyz[j * 3 + 2] - xyz[n * 3 + 2];
    float f0 = x[j * 4 + 0] - x[n * 4 + 0];
    float f1 = x[j * 4 + 1] - x[n * 4 + 1];
    float f2 = x[j * 4 + 2] - x[n * 4 + 2];
    float f3 = x[j * 4 + 3] - x[n * 4 + 3];
    sf[c][0] = f0 * f0; sf[c][1] = f1 * f1;
    sf[c][2] = f2 * f2; sf[c][3] = f3 * f3;
  }
  __syncthreads();
  const float m0 = sm[c], m1 = sm[CH + c], m2 = sm[2 * CH + c];
  const float m4 = sm[4 * CH + c], m5 = sm[5 * CH + c], m6 = sm[6 * CH + c];
  const float m8 = sm[8 * CH + c], m9 = sm[9 * CH + c], m10 = sm[10 * CH + c];
  float c0 = sc[c];          c0 *= c0;
  float c1 = sc[CH + c];     c1 *= c1;
  float c2 = sc[2 * CH + c]; c2 *= c2;
  float h2 = sh[c];          h2 *= h2;
  float e = 0.0f;
#pragma unroll
  for (int k = 0; k < KNB; k++) {
    const float r0 = sr[k][0], r1 = sr[k][1], r2 = sr[k][2];
    const float d0 = fmaf(r2, m2, fmaf(r1, m1, r0 * m0));
    const float d1 = fmaf(r2, m6, fmaf(r1, m5, r0 * m4));
    const float d2 = fmaf(r2, m10, fmaf(r1, m9, r0 * m8));
    e = fmaf(d0, d0, e);
    e = fmaf(d1, d1, e);
    e = fmaf(d2, d2, e);
    e = fmaf(sf[k][0], c0, e);
    e = fmaf(sf[k][1], c1, e);
    e = fmaf(sf[k][2], c2, e);
    e = fmaf(sf[k][3], h2, e);
  }
  const float v = sqrtf(e * (1.0f / KNB)) * bnscale(g0[c]) + b0[c];
  u16 hi, lo; bf16split(v, hi, lo);
  const size_t idx = (size_t)n * CH + c;
  oh[idx] = hi; ol[idx] = lo;
}

// ---------------- LFP gather + PE + max + BN + residual (+ optional fused lproj) ----
// 256 thr = 16 points, 16 lanes/point, 8 ch/lane, 16B bf16x8 gathers.
// XP: after updating h, compute xpo = h_new_hi @ proj (per-row, block-local) via MFMA.
template <bool XP>
__global__ __launch_bounds__(256) void lfp_kernel(
    const u16* __restrict__ xp, const int* __restrict__ knn,
    const float* __restrict__ xyz, const float* __restrict__ coor,
    const float* __restrict__ scale, const float* __restrict__ g,
    const float* __restrict__ b, const u16* __restrict__ pjh,
    const u16* __restrict__ pjl, u16* __restrict__ xpo,
    u16* __restrict__ hh, u16* __restrict__ hl) {
  const int t = threadIdx.x;
  const int bid = blockIdx.x;
  __shared__ int si[16][KNB];
  __shared__ float sr[16][KNB][3];
  __shared__ __align__(16) u16 Hs[16 * 128];
  {
    const int pp = t >> 4, kk = t & 15;
    const int n = bid * 16 + pp;
    const int j = knn[n * KNB + kk];
    si[pp][kk] = j;
    sr[pp][kk][0] = xyz[j * 3 + 0] - xyz[n * 3 + 0];
    sr[pp][kk][1] = xyz[j * 3 + 1] - xyz[n * 3 + 1];
    sr[pp][kk][2] = xyz[j * 3 + 2] - xyz[n * 3 + 2];
  }
  __syncthreads();
  const int p = t >> 4, d8 = t & 15;   // channels c = d8*8 .. d8*8+7
  const int n = bid * 16 + p;
  const float c0a = coor[d8 * 2],     c1a = coor[32 + d8 * 2],     c2a = coor[64 + d8 * 2];
  const float c0b = coor[d8 * 2 + 1], c1b = coor[32 + d8 * 2 + 1], c2b = coor[64 + d8 * 2 + 1];
  float s2a = scale[d8 * 2];     s2a *= s2a;
  float s2b = scale[d8 * 2 + 1]; s2b *= s2b;
  float a[8];
#pragma unroll
  for (int e = 0; e < 8; e++) a[e] = -3.0e38f;
#pragma unroll
  for (int k = 0; k < KNB; k++) {
    const int j = si[p][k];
    const float r0 = sr[p][k][0], r1 = sr[p][k][1], r2 = sr[p][k][2];
    const float pea = fmaf(r2, c2a, fmaf(r1, c1a, r0 * c0a)) * s2a;
    const float peb = fmaf(r2, c2b, fmaf(r1, c1b, r0 * c0b)) * s2b;
    const bf16x8 v = *(const bf16x8*)(xp + (size_t)j * CH + d8 * 8);
#pragma unroll
    for (int e = 0; e < 4; e++) a[e] = fmaxf(a[e], bf2f((u16)v[e]) + pea);
#pragma unroll
    for (int e = 4; e < 8; e++) a[e] = fmaxf(a[e], bf2f((u16)v[e]) + peb);
  }
  const size_t off = (size_t)n * CH + d8 * 8;
  union { u16 a[8]; uint4 v; } ih, il, oh, ol;
  ih.v = *(const uint4*)(hh + off);
  il.v = *(const uint4*)(hl + off);
#pragma unroll
  for (int e = 0; e < 8; e++) {
    const int c = d8 * 8 + e;
    const float nv = bf2f(ih.a[e]) + bf2f(il.a[e]) + a[e] * bnscale(g[c]) + b[c];
    u16 hi, lo; bf16split(nv, hi, lo);
    oh.a[e] = hi; ol.a[e] = lo;
  }
  *(uint4*)(hh + off) = oh.v;
  *(uint4*)(hl + off) = ol.v;

  if constexpr (XP) {
    {  // stash new h-hi in LDS, 64-window XOR swizzle
      const int c0 = d8 * 8;
      const int cs0 = (c0 & ~63) | ((c0 & 63) ^ ((p & 7) << 3));
      *(uint4*)(Hs + p * 128 + cs0) = oh.v;
    }
    __syncthreads();
    const int lane = t & 63, w = t >> 6;
    const int lc = lane & 15, lq = lane >> 4;
    const int lq8 = lq * 8, lq4 = lq * 4;
    bf16x8 ph_[2][4], pl_[2][4];
#pragma unroll
    for (int nf = 0; nf < 2; nf++)
#pragma unroll
      for (int ks = 0; ks < 4; ks++) {
        const size_t wo = (size_t)(w * 32 + nf * 16 + lc) * 128 + ks * 32 + lq8;
        ph_[nf][ks] = *(const bf16x8*)(pjh + wo);
        pl_[nf][ks] = *(const bf16x8*)(pjl + wo);
      }
    const f32x4 zz = {0.0f, 0.0f, 0.0f, 0.0f};
    f32x4 xacc[2] = {zz, zz};
#pragma unroll
    for (int ks = 0; ks < 4; ks++) {
      const int j = ks * 32 + lq8;
      const int cs = (j & ~63) | ((j & 63) ^ ((lc & 7) << 3));
      const bf16x8 aF = *(const bf16x8*)(Hs + lc * 128 + cs);
#pragma unroll
      for (int nf = 0; nf < 2; nf++) {
        xacc[nf] = __builtin_amdgcn_mfma_f32_16x16x32_bf16(aF, ph_[nf][ks], xacc[nf], 0, 0, 0);
        xacc[nf] = __builtin_amdgcn_mfma_f32_16x16x32_bf16(aF, pl_[nf][ks], xacc[nf], 0, 0, 0);
      }
    }
#pragma unroll
    for (int q = 0; q < 4; q++)
#pragma unroll
      for (int nf = 0; nf < 2; nf++)
        xpo[(size_t)(bid * 16 + lq4 + q) * CH + w * 32 + nf * 16 + lc] =
            f2bf(xacc[nf][q]);
  }
}

// ---------------- weight prep: transpose + bf16 hi/lo (+64-window swizzle for w2) ----
__global__ __launch_bounds__(256) void prep_weights(
    const float* __restrict__ nw1, const float* __restrict__ nw2,
    const float* __restrict__ mw1, const float* __restrict__ mw2,
    const float* __restrict__ lproj, const float* __restrict__ pw,
    const float* __restrict__ pg, u16* __restrict__ th, u16* __restrict__ tl) {
  const int idx = blockIdx.x * 256 + threadIdx.x;
  const float* src;
  int local, Kd, Nd, dst, swz;
  float scale = 1.0f;
  if (idx < 32768)        { src = nw1; local = idx;          Kd = 128; Nd = 256; dst = 0; swz = 0; }
  else if (idx < 65536)   { src = nw2; local = idx - 32768;  Kd = 256; Nd = 128; dst = 32768; swz = 1; }
  else if (idx < 262144)  { int j = (idx - 65536) >> 16;  local = (idx - 65536) & 65535;
                            src = mw1 + j * 65536; Kd = 128; Nd = 512; dst = 65536 + j * 65536; swz = 0; }
  else if (idx < 458752)  { int j = (idx - 262144) >> 16; local = (idx - 262144) & 65535;
                            src = mw2 + j * 65536; Kd = 512; Nd = 128; dst = 262144 + j * 65536; swz = 1; }
  else if (idx < 524288)  { int i = (idx - 458752) >> 14; local = (idx - 458752) & 16383;
                            src = lproj + i * 16384; Kd = 128; Nd = 128; dst = 458752 + i * 16384; swz = 0; }
  else if (idx < 557056)  { local = idx - 524288; src = pw; Kd = 128; Nd = 256; dst = 524288; swz = 0;
                            scale = bnscale(pg[local >> 8]); }
  else return;
  const int k = local / Nd, n = local % Nd;
  const float v = src[local] * scale;
  u16 hi, lo; bf16split(v, hi, lo);
  const int ks = swz ? ((k & ~63) | ((k & 63) ^ ((n & 7) << 3))) : k;
  const int o = dst + n * Kd + ks;
  th[o] = hi; tl[o] = lo;
}

// folded post bias: fb[n] = sum_k pb[k] * pw[k][n]
__global__ __launch_bounds__(256) void fold_pb(const float* __restrict__ pw,
                                               const float* __restrict__ pb,
                                               float* __restrict__ fb) {
  const int t = threadIdx.x;
  float a = 0.0f;
  for (int k = 0; k < 128; k++) a = fmaf(pb[k], pw[k * 256 + t], a);
  fb[t] = a;
}

// ---------------- barrier-free streaming K=128 GEMM, W in registers ----------------
// NSPLIT: 3 = Ahi*Bhi+Ahi*Blo+Alo*Bhi (exact-ish), 2 = Ahi*Bhi+Ahi*Blo (A-hi only).
// EPI: 1 -> gelu(v+bias) -> u16 act; 2 -> v+bias -> f32 out
template <int EPI, int NSPLIT>
__global__ __launch_bounds__(256, 2) void k128_reg(
    const u16* __restrict__ Ahi, const u16* __restrict__ Alo,
    const u16* __restrict__ Wth, const u16* __restrict__ Wtl,
    const float* __restrict__ p0, u16* __restrict__ outu,
    float* __restrict__ outf, int ostride, int ntiles) {
  const int t = threadIdx.x, lane = t & 63, w = t >> 6;
  const int col0 = blockIdx.y * 128;
  const int wm0 = (w >> 1) * 32, wn0 = (w & 1) * 64;
  const int lc = lane & 15, lq = lane >> 4;
  const int lq8 = lq * 8, lq4 = lq * 4;

  bf16x8 wh[4][4], wl[4][4];
  float bv[4];
#pragma unroll
  for (int nf = 0; nf < 4; nf++) {
    const int nr = col0 + wn0 + nf * 16 + lc;
    const u16* wr = Wth + (size_t)nr * 128;
    const u16* wr2 = Wtl + (size_t)nr * 128;
#pragma unroll
    for (int ks = 0; ks < 4; ks++) {
      wh[nf][ks] = *(const bf16x8*)(wr + ks * 32 + lq8);
      wl[nf][ks] = *(const bf16x8*)(wr2 + ks * 32 + lq8);
    }
    bv[nf] = p0[nr];
  }

  const f32x4 zz = {0.0f, 0.0f, 0.0f, 0.0f};
  for (int tile = blockIdx.x; tile < ntiles; tile += gridDim.x) {
    const int row0 = tile * 64;
    f32x4 acc[2][4];
#pragma unroll
    for (int mf = 0; mf < 2; mf++)
#pragma unroll
      for (int nf = 0; nf < 4; nf++) acc[mf][nf] = zz;
#pragma unroll
    for (int ks = 0; ks < 4; ks++) {
      bf16x8 ah[2], al[2];
#pragma unroll
      for (int mf = 0; mf < 2; mf++) {
        const size_t ao = (size_t)(row0 + wm0 + mf * 16 + lc) * 128 + ks * 32 + lq8;
        ah[mf] = *(const bf16x8*)(Ahi + ao);
        if (NSPLIT == 3) al[mf] = *(const bf16x8*)(Alo + ao);
      }
#pragma unroll
      for (int mf = 0; mf < 2; mf++)
#pragma unroll
        for (int nf = 0; nf < 4; nf++) {
          acc[mf][nf] = __builtin_amdgcn_mfma_f32_16x16x32_bf16(ah[mf], wh[nf][ks], acc[mf][nf], 0, 0, 0);
          acc[mf][nf] = __builtin_amdgcn_mfma_f32_16x16x32_bf16(ah[mf], wl[nf][ks], acc[mf][nf], 0, 0, 0);
          if (NSPLIT == 3)
            acc[mf][nf] = __builtin_amdgcn_mfma_f32_16x16x32_bf16(al[mf], wh[nf][ks], acc[mf][nf], 0, 0, 0);
        }
    }
#pragma unroll
    for (int mf = 0; mf < 2; mf++)
#pragma unroll
      for (int q = 0; q < 4; q++) {
        const int r = row0 + wm0 + mf * 16 + lq4 + q;
#pragma unroll
        for (int nf = 0; nf < 4; nf++) {
          const int col = col0 + wn0 + nf * 16 + lc;
          const size_t off = (size_t)r * ostride + col;
          const float v = acc[mf][nf][q];
          if (EPI == 1) outu[off] = f2bf(gelu_f(v + bv[nf]));
          else          outf[off] = v + bv[nf];
        }
      }
  }
}

// ---------------- w2 GEMM v3 + optional fused lproj ----------------
// h' = [h +] BN(act[M x K] @ W2[K x 128]); BM=64 (625 exact blocks), all 128 cols.
// W2-hi double-buffered in LDS (16 KB/buf, 64-window XOR swizzle); W2-lo direct
// from L2-hot global; act frags global->reg prefetched 1 slab ahead. 1 barrier/iter.
// XP: epilogue additionally computes xpo = h'_hi @ proj (block-local rows).
template <int K, bool RES, bool XP>
__global__ __launch_bounds__(256, 3) void gemm_w2(
    const u16* __restrict__ A, const u16* __restrict__ Wth,
    const u16* __restrict__ Wtl, const float* __restrict__ g,
    const float* __restrict__ bb, const u16* __restrict__ pjh,
    const u16* __restrict__ pjl, u16* __restrict__ xpo,
    u16* __restrict__ hh, u16* __restrict__ hl) {
  __shared__ __align__(16) u16 Ws[2][128 * 64];   // [buf][n=128][k=64]
  const int t = threadIdx.x, lane = t & 63, w = t >> 6;
  const int row0 = blockIdx.x * 64;
  const int wm0 = (w >> 1) * 32, wn0 = (w & 1) * 64;
  const int lc = lane & 15, lq = lane >> 4;
  const int lq8 = lq * 8, lq4 = lq * 4;

  const f32x4 zz = {0.0f, 0.0f, 0.0f, 0.0f};
  f32x4 acc[2][4];
#pragma unroll
  for (int mf = 0; mf < 2; mf++)
#pragma unroll
    for (int nf = 0; nf < 4; nf++) acc[mf][nf] = zz;

  auto stage_slab = [&](u16* lds, int kb) {
#pragma unroll
    for (int i = 0; i < 1024; i += 256) {       // 1024 chunks of 16B
      const int wc0 = i + w * 64;
      const int c = wc0 + lane;
      gl2lds(Wth + (size_t)(c >> 3) * K + kb + (c & 7) * 8, lds + wc0 * 8);
    }
  };
  auto load_af = [&](bf16x8 (&dst)[2][2], int kb) {
#pragma unroll
    for (int mf = 0; mf < 2; mf++)
#pragma unroll
      for (int ks = 0; ks < 2; ks++)
        dst[mf][ks] = *(const bf16x8*)(A + (size_t)(row0 + wm0 + mf * 16 + lc) * K +
                                       kb + ks * 32 + lq8);
  };

  bf16x8 afc[2][2], afn[2][2];
  stage_slab(Ws[0], 0);
  load_af(afc, 0);
  __syncthreads();

  constexpr int NT = K / 64;
#pragma unroll 2
  for (int tt = 0; tt < NT; tt++) {
    const int cur = tt & 1;
    if (tt + 1 < NT) {
      stage_slab(Ws[cur ^ 1], (tt + 1) * 64);   // async, flies under MFMA
      load_af(afn, (tt + 1) * 64);              // reg prefetch
    }
#pragma unroll
    for (int ks = 0; ks < 2; ks++) {
      bf16x8 whf[4], wlf[4];
#pragma unroll
      for (int nf = 0; nf < 4; nf++) {
        const int nr = wn0 + nf * 16 + lc;
        const int j = (ks * 32 + lq8) ^ ((nr & 7) << 3);
        whf[nf] = *(const bf16x8*)(Ws[cur] + nr * 64 + j);
        wlf[nf] = *(const bf16x8*)(Wtl + (size_t)nr * K + tt * 64 + j);
      }
#pragma unroll
      for (int mf = 0; mf < 2; mf++)
#pragma unroll
        for (int nf = 0; nf < 4; nf++) {
          acc[mf][nf] = __builtin_amdgcn_mfma_f32_16x16x32_bf16(afc[mf][ks], whf[nf], acc[mf][nf], 0, 0, 0);
          acc[mf][nf] = __builtin_amdgcn_mfma_f32_16x16x32_bf16(afc[mf][ks], wlf[nf], acc[mf][nf], 0, 0, 0);
        }
    }
    __syncthreads();   // drains next-slab stage; guards buf reuse
#pragma unroll
    for (int mf = 0; mf < 2; mf++)
#pragma unroll
      for (int ks = 0; ks < 2; ks++) afc[mf][ks] = afn[mf][ks];
  }

  u16* Hs = &Ws[0][0];   // reuse: 64 x 128 u16 = 16 KB (safe: post-loop barrier done)
  float S0[4], S1[4];
#pragma unroll
  for (int nf = 0; nf < 4; nf++) {
    const int col = wn0 + nf * 16 + lc;
    S0[nf] = bnscale(g[col]);
    S1[nf] = bb[col];
  }
#pragma unroll
  for (int mf = 0; mf < 2; mf++)
#pragma unroll
    for (int q = 0; q < 4; q++) {
      const int r = row0 + wm0 + mf * 16 + lq4 + q;
#pragma unroll
      for (int nf = 0; nf < 4; nf++) {
        const int col = wn0 + nf * 16 + lc;
        const size_t off = (size_t)r * CH + col;
        float v = acc[mf][nf][q] * S0[nf] + S1[nf];
        if (RES) v += bf2f(hh[off]) + bf2f(hl[off]);
        u16 hi, lo; bf16split(v, hi, lo);
        hh[off] = hi; hl[off] = lo;
        if constexpr (XP) {
          const int rl = wm0 + mf * 16 + lq4 + q;
          const int cs = (col & ~63) | ((col & 63) ^ ((rl & 7) << 3));
          Hs[rl * 128 + cs] = hi;
        }
      }
    }

  if constexpr (XP) {
    __syncthreads();   // Hs complete
    // wave w computes all 64 rows x cols [w*32, w*32+32)
    bf16x8 ph_[2][4], pl_[2][4];
#pragma unroll
    for (int nf = 0; nf < 2; nf++)
#pragma unroll
      for (int ks = 0; ks < 4; ks++) {
        const size_t wo = (size_t)(w * 32 + nf * 16 + lc) * 128 + ks * 32 + lq8;
        ph_[nf][ks] = *(const bf16x8*)(pjh + wo);
        pl_[nf][ks] = *(const bf16x8*)(pjl + wo);
      }
    f32x4 xacc[4][2];
#pragma unroll
    for (int mf = 0; mf < 4; mf++)
#pragma unroll
      for (int nf = 0; nf < 2; nf++) xacc[mf][nf] = zz;
#pragma unroll
    for (int ks = 0; ks < 4; ks++) {
      const int j = ks * 32 + lq8;
      bf16x8 aF[4];
#pragma unroll
      for (int mf = 0; mf < 4; mf++) {
        const int r = mf * 16 + lc;
        const int cs = (j & ~63) | ((j & 63) ^ ((r & 7) << 3));
        aF[mf] = *(const bf16x8*)(Hs + r * 128 + cs);
      }
#pragma unroll
      for (int mf = 0; mf < 4; mf++)
#pragma unroll
        for (int nf = 0; nf < 2; nf++) {
          xacc[mf][nf] = __builtin_amdgcn_mfma_f32_16x16x32_bf16(aF[mf], ph_[nf][ks], xacc[mf][nf], 0, 0, 0);
          xacc[mf][nf] = __builtin_amdgcn_mfma_f32_16x16x32_bf16(aF[mf], pl_[nf][ks], xacc[mf][nf], 0, 0, 0);
        }
    }
#pragma unroll
    for (int mf = 0; mf < 4; mf++)
#pragma unroll
      for (int q = 0; q < 4; q++)
#pragma unroll
        for (int nf = 0; nf < 2; nf++)
          xpo[(size_t)(row0 + mf * 16 + lq4 + q) * CH + w * 32 + nf * 16 + lc] =
              f2bf(xacc[mf][nf][q]);
  }
}

extern "C" void kernel_launch(void* const* d_in, const int* in_sizes, int n_in,
                              void* d_out, int out_size, void* d_ws, size_t ws_size,
                              hipStream_t stream) {
  const float* x    = (const float*)d_in[0];
  const float* xyz  = (const float*)d_in[1];
  const int*   knn  = (const int*)d_in[2];
  const float* sm   = (const float*)d_in[3];
  const float* scc  = (const float*)d_in[4];
  const float* shh  = (const float*)d_in[5];
  const float* bn0g = (const float*)d_in[6];
  const float* bn0b = (const float*)d_in[7];
  const float* nw1  = (const float*)d_in[8];
  const float* nb1  = (const float*)d_in[9];
  const float* nw2  = (const float*)d_in[10];
  const float* nbng = (const float*)d_in[11];
  const float* nbnb = (const float*)d_in[12];
  const float* lproj  = (const float*)d_in[13];
  const float* lcoor  = (const float*)d_in[14];
  const float* lscale = (const float*)d_in[15];
  const float* lbng   = (const float*)d_in[16];
  const float* lbnb   = (const float*)d_in[17];
  const float* mw1  = (const float*)d_in[18];
  const float* mb1  = (const float*)d_in[19];
  const float* mw2  = (const float*)d_in[20];
  const float* mbng = (const float*)d_in[21];
  const float* mbnb = (const float*)d_in[22];
  const float* pg   = (const float*)d_in[23];
  const float* pb   = (const float*)d_in[24];
  const float* pw   = (const float*)d_in[25];
  float* out = (float*)d_out;

  // workspace (bytes)
  char* ws = (char*)d_ws;
  u16*   h_hi = (u16*)(ws + 0);              // 10,240,000
  u16*   h_lo = (u16*)(ws + 10240000);       // 10,240,000
  u16*   act  = (u16*)(ws + 20480000);       // 40,960,000 (40000x512 bf16-hi)
  u16*   xpA  = (u16*)(ws + 61440000);       // 10,240,000
  u16*   xpB  = (u16*)(ws + 71680000);       // 10,240,000
  u16*   Wh   = (u16*)(ws + 81920000);       // 1,114,112
  u16*   Wl   = (u16*)(ws + 83034112);       // 1,114,112
  float* fb   = (float*)(ws + 84148224);     // 1,024

  const u16* nw1t   = Wh + 0;
  const u16* nw2t   = Wh + 32768;
  const u16* mw1t   = Wh + 65536;
  const u16* mw2t   = Wh + 262144;
  const u16* lprojt = Wh + 458752;
  const u16* postt  = Wh + 524288;
  const u16* nw1tl   = Wl + 0;
  const u16* nw2tl   = Wl + 32768;
  const u16* mw1tl   = Wl + 65536;
  const u16* mw2tl   = Wl + 262144;
  const u16* lprojtl = Wl + 458752;
  const u16* posttl  = Wl + 524288;

  prep_weights<<<2176, 256, 0, stream>>>(nw1, nw2, mw1, mw2, lproj, pw, pg, Wh, Wl);
  fold_pb<<<1, 256, 0, stream>>>(pw, pb, fb);

  spse_kernel<<<NPTS, 128, 0, stream>>>(x, xyz, knn, sm, scc, shh, bn0g, bn0b, h_hi, h_lo);

  // nbr_proj: act = gelu(nbr@w1+b1); h = BN(act@w2)   [no xp emit]
  k128_reg<1, 2><<<dim3(256, 2), 256, 0, stream>>>(h_hi, h_lo, nw1t, nw1tl, nb1,
                                                   act, nullptr, 256, 625);
  gemm_w2<256, false, false><<<625, 256, 0, stream>>>(
      act, nw2t, nw2tl, nbng, nbnb, nullptr, nullptr, nullptr, h_hi, h_lo);

  // mlp 0 (residual) -> h2, fused lproj0 -> xpA
  k128_reg<1, 2><<<dim3(128, 4), 256, 0, stream>>>(h_hi, h_lo, mw1t, mw1tl, mb1,
                                                   act, nullptr, 512, 625);
  gemm_w2<512, true, true><<<625, 256, 0, stream>>>(
      act, mw2t, mw2tl, mbng, mbnb, lprojt, lprojtl, xpA, h_hi, h_lo);

  // i=0: lfp0 reads xpA -> h3, fused lproj1 -> xpB
  lfp_kernel<true><<<2500, 256, 0, stream>>>(
      xpA, knn, xyz, lcoor + 0 * 96, lscale + 0 * 32, lbng + 0 * 128, lbnb + 0 * 128,
      lprojt + 16384, lprojtl + 16384, xpB, h_hi, h_lo);

  // i=1: lfp1 reads xpB -> h4 (no xp); mlp1 -> h5, fused lproj2 -> xpA
  lfp_kernel<false><<<2500, 256, 0, stream>>>(
      xpB, knn, xyz, lcoor + 1 * 96, lscale + 1 * 32, lbng + 1 * 128, lbnb + 1 * 128,
      nullptr, nullptr, nullptr, h_hi, h_lo);
  k128_reg<1, 2><<<dim3(128, 4), 256, 0, stream>>>(h_hi, h_lo, mw1t + 65536,
                                                   mw1tl + 65536, mb1 + 512,
                                                   act, nullptr, 512, 625);
  gemm_w2<512, true, true><<<625, 256, 0, stream>>>(
      act, mw2t + 65536, mw2tl + 65536, mbng + 128, mbnb + 128,
      lprojt + 2 * 16384, lprojtl + 2 * 16384, xpA, h_hi, h_lo);

  // i=2: lfp2 reads xpA -> h6, fused lproj3 -> xpB
  lfp_kernel<true><<<2500, 256, 0, stream>>>(
      xpA, knn, xyz, lcoor + 2 * 96, lscale + 2 * 32, lbng + 2 * 128, lbnb + 2 * 128,
      lprojt + 3 * 16384, lprojtl + 3 * 16384, xpB, h_hi, h_lo);

  // i=3: lfp3 reads xpB -> h7 (no xp); mlp2 -> h8 (no xp)
  lfp_kernel<false><<<2500, 256, 0, stream>>>(
      xpB, knn, xyz, lcoor + 3 * 96, lscale + 3 * 32, lbng + 3 * 128, lbnb + 3 * 128,
      nullptr, nullptr, nullptr, h_hi, h_lo);
  k128_reg<1, 2><<<dim3(128, 4), 256, 0, stream>>>(h_hi, h_lo, mw1t + 2 * 65536,
                                                   mw1tl + 2 * 65536, mb1 + 2 * 512,
                                                   act, nullptr, 512, 625);
  gemm_w2<512, true, false><<<625, 256, 0, stream>>>(
      act, mw2t + 2 * 65536, mw2tl + 2 * 65536, mbng + 2 * 128, mbnb + 2 * 128,
      nullptr, nullptr, nullptr, h_hi, h_lo);

  // postproj (BN folded into weights; rank-1 bias) — exact 3-split
  k128_reg<2, 3><<<dim3(256, 2), 256, 0, stream>>>(h_hi, h_lo, postt, posttl, fb,
                                                   nullptr, out, 256, 625);
}